// Round 2
// baseline (1372.701 us; speedup 1.0000x reference)
//
#include <hip/hip_runtime.h>
#include <math.h>

#define GAMMA_   0.97f
#define LAM_     0.95f
#define EPSILON_ 0.3f
#define HLOG2PI_ 0.91893853320467274f
#define LOG2C_   0.69314718055994531f
#define LOG1P2_  0.18232155679395463f
#define LOG0P8_  (-0.22314355131420976f)

typedef unsigned short u16;
typedef unsigned int   u32;
typedef _Float16 half8 __attribute__((ext_vector_type(8)));
typedef __attribute__((ext_vector_type(4))) float floatx4;
typedef __attribute__((ext_vector_type(8))) float floatx8;

constexpr int  TT     = 1024;
constexpr long ROWS_P = (long)TT * 256;          // 262144
constexpr long ROWS_V = (long)(TT + 1) * 256;    // 262400

// ---- fragment workspace layout (u16 offsets from ws base) ----
constexpr long FR_W0P_HI = 0;        // NT16 KS2  -> 16384
constexpr long FR_W0P_LO = 16384;
constexpr long FR_W1P_HI = 32768;    // NT16 KS8  -> 65536
constexpr long FR_W1P_LO = 98304;
constexpr long FR_W2P_HI = 163840;   // NT1  KS8  -> 4096
constexpr long FR_W2P_LO = 167936;
constexpr long FR_W0V_HI = 172032;
constexpr long FR_W0V_LO = 188416;
constexpr long FR_W1V_HI = 204800;
constexpr long FR_W1V_LO = 270336;
constexpr long FR_W2V_HI = 335872;
constexpr long FR_W2V_LO = 339968;
constexpr long FR_TOTAL  = 344064;   // u16 elems

// ---- float workspace (offsets from (float*)ws + FR_TOTAL/2) ----
constexpr long WS_ACC  = 0;                 // 32
constexpr long WS_INV  = 32;                // 64
constexpr long WS_ADV  = 96;                // 262144
constexpr long WS_BASE = WS_ADV + ROWS_P;   // 262400
constexpr long WS_GA   = WS_BASE + ROWS_V;  // 8192
constexpr long WS_GP   = WS_GA + 8192;
constexpr long WS_GS   = WS_GP + 8192;

// accum slots: 0 kl_sum, 1 kl_m_sum, 2 ent_sum, 3 adv_sum, 4 adv2_sum,
//              5 vmx2_sum, 6 gp_sum, 7 lp_sum

__device__ __forceinline__ float softplus_f(float x) {
  return (x > 20.f) ? x : log1pf(expf(x));
}
// silu: result is truncated to fp16 downstream, so v_rcp_f32 (~2^-22 rel err)
// is exact at the storage precision and saves the precise-div sequence.
__device__ __forceinline__ float silu_f(float x) {
  return x * __builtin_amdgcn_rcpf(1.f + __expf(-x));
}
__device__ __forceinline__ float clamp30(float x) {
  return fminf(1e30f, fmaxf(-1e30f, x));
}

// ---------------- prep ----------------
__global__ void prep_kernel(const float* __restrict__ rv,
                            float* __restrict__ inv_std,
                            float* __restrict__ accum) {
  int t = threadIdx.x;
  if (t < 32) accum[t] = 0.f;
  if (t < 64) {
    float var = rv[t] / 1000001.0f;
    var = fminf(1e6f, fmaxf(1e-6f, var));
    inv_std[t] = 1.f / sqrtf(var);
  }
}

// ---------------- weight -> split-fp16 MFMA fragments ----------------
__global__ void convert_kernel(const float* __restrict__ pw0,
                               const float* __restrict__ pw1,
                               const float* __restrict__ pw2,
                               const float* __restrict__ vw0,
                               const float* __restrict__ vw1,
                               const float* __restrict__ vw2,
                               u16* __restrict__ frag) {
  int idx = blockIdx.x * 256 + threadIdx.x;   // 0..172031
  const float* W; int kslog, K, nvalid; long hioff, looff; int e;
  if (idx < 16384)       { W = pw0; e = idx;          kslog = 1; K = 64;  nvalid = 256; hioff = FR_W0P_HI; looff = FR_W0P_LO; }
  else if (idx < 81920)  { W = pw1; e = idx - 16384;  kslog = 3; K = 256; nvalid = 256; hioff = FR_W1P_HI; looff = FR_W1P_LO; }
  else if (idx < 86016)  { W = pw2; e = idx - 81920;  kslog = 3; K = 256; nvalid = 16;  hioff = FR_W2P_HI; looff = FR_W2P_LO; }
  else if (idx < 102400) { W = vw0; e = idx - 86016;  kslog = 1; K = 64;  nvalid = 256; hioff = FR_W0V_HI; looff = FR_W0V_LO; }
  else if (idx < 167936) { W = vw1; e = idx - 102400; kslog = 3; K = 256; nvalid = 256; hioff = FR_W1V_HI; looff = FR_W1V_LO; }
  else                   { W = vw2; e = idx - 167936; kslog = 3; K = 256; nvalid = 1;   hioff = FR_W2V_HI; looff = FR_W2V_LO; }
  int j    = e & 7;
  int lane = (e >> 3) & 63;
  int ks   = (e >> 9) & ((1 << kslog) - 1);
  int nt   = e >> (9 + kslog);
  int n = nt * 16 + (lane & 15);
  int k = ks * 32 + ((lane >> 4) << 3) + j;
  float w = (n < nvalid) ? W[n * K + k] : 0.f;
  _Float16 hi = (_Float16)w;
  _Float16 lo = (_Float16)(w - (float)hi);
  frag[hioff + e] = *(u16*)&hi;
  frag[looff + e] = *(u16*)&lo;
}

// LDS strides (fp16 units); multiples of 8 (16B-aligned rows)
constexpr int SX = 72;    // X row stride
constexpr int SH = 264;   // H row stride

// =====================================================================
// Policy: block = 32 obs rows (vrows 0..31) + same 32 pobs rows (32..63).
// 4 waves; wave wv owns ntile quarter (4 ntiles = 64 cols) x ALL 4 mtiles
// (reuse-4 on B), B double-buffered. fp16 1-plane acts, 2-plane weights.
// This revision: occupancy 3 -> 4 blocks/CU (LDS 38912*4 = 155648 fits
// the 160 KiB pool; VGPR 84 < 128), rcp-based silu.
// =====================================================================
__global__ __launch_bounds__(256, 4)
void policy_kernel(const float* __restrict__ obs,
                   const float* __restrict__ pobs,
                   const float* __restrict__ rm,
                   const float* __restrict__ inv_std,
                   const u16* __restrict__ frag,
                   const float* __restrict__ b0,
                   const float* __restrict__ b1,
                   const float* __restrict__ b2,
                   const float* __restrict__ logits,
                   const float* __restrict__ action,
                   const float* __restrict__ noise,
                   const float* __restrict__ adv,
                   float* __restrict__ accum) {
  __shared__ __align__(16) _Float16 H[64 * SH];   // 33792 B, X aliases in
  __shared__ float OUTT[64 * 16];
  __shared__ float red[160];

  const int tid  = threadIdx.x;
  const long row0 = (long)blockIdx.x * 32;
  const int lane = tid & 63;
  const int wv   = tid >> 6;         // ntile quarter
  const int lm   = lane & 15;
  const int lq   = lane >> 4;

  _Float16* X = H;                   // X dead after L1 MFMA

  // ---- stage normalized X (vrows 0..31 obs, 32..63 pobs), vectorized ----
  #pragma unroll
  for (int it = 0; it < 2; ++it) {
    int flat = it * 256 + tid;       // 512 groups of 8 floats
    int vr = flat >> 3;
    int f0 = (flat & 7) * 8;
    const float* src = (vr < 32) ? obs : pobs;
    floatx8 v  = *(const floatx8*)&src[(row0 + (vr & 31)) * 64 + f0];
    floatx8 m  = *(const floatx8*)&rm[f0];
    floatx8 is = *(const floatx8*)&inv_std[f0];
    half8 h;
    #pragma unroll
    for (int j = 0; j < 8; ++j)
      h[j] = (_Float16)fminf(5.f, fmaxf(-5.f, (v[j] - m[j]) * is[j]));
    *(half8*)&X[vr * SX + f0] = h;
  }

  // ---- prefetch L1 B fragments (global only, safe across barrier) ----
  const half8* B0h = (const half8*)(frag + FR_W0P_HI);
  const half8* B0l = (const half8*)(frag + FR_W0P_LO);
  half8 B0hr[2][4], B0lr[2][4];
  #pragma unroll
  for (int ks = 0; ks < 2; ++ks)
    #pragma unroll
    for (int nt = 0; nt < 4; ++nt) {
      int ntg = wv * 4 + nt;
      B0hr[ks][nt] = B0h[(ntg * 2 + ks) * 64 + lane];
      B0lr[ks][nt] = B0l[(ntg * 2 + ks) * 64 + lane];
    }
  __syncthreads();

  floatx4 acc[4][4];

  // ---- layer 1: K=64 (2 ksteps) ----
  #pragma unroll
  for (int mt = 0; mt < 4; ++mt)
    #pragma unroll
    for (int nt = 0; nt < 4; ++nt) acc[mt][nt] = (floatx4){0.f,0.f,0.f,0.f};
  #pragma unroll
  for (int ks = 0; ks < 2; ++ks) {
    half8 A[4];
    #pragma unroll
    for (int mt = 0; mt < 4; ++mt)
      A[mt] = *(const half8*)&X[(mt * 16 + lm) * SX + ks * 32 + lq * 8];
    __builtin_amdgcn_s_setprio(1);
    #pragma unroll
    for (int mt = 0; mt < 4; ++mt)
      #pragma unroll
      for (int nt = 0; nt < 4; ++nt)
        acc[mt][nt] = __builtin_amdgcn_mfma_f32_16x16x32_f16(A[mt], B0hr[ks][nt], acc[mt][nt], 0, 0, 0);
    #pragma unroll
    for (int mt = 0; mt < 4; ++mt)
      #pragma unroll
      for (int nt = 0; nt < 4; ++nt)
        acc[mt][nt] = __builtin_amdgcn_mfma_f32_16x16x32_f16(A[mt], B0lr[ks][nt], acc[mt][nt], 0, 0, 0);
    __builtin_amdgcn_s_setprio(0);
  }

  // ---- prefetch L2 ks=0 B fragments before the epilogue barrier ----
  const half8* B1h = (const half8*)(frag + FR_W1P_HI);
  const half8* B1l = (const half8*)(frag + FR_W1P_LO);
  half8 Bh[4], Bl[4], Bhn[4], Bln[4];
  #pragma unroll
  for (int nt = 0; nt < 4; ++nt) {
    int ntg = wv * 4 + nt;
    Bh[nt] = B1h[(ntg * 8) * 64 + lane];
    Bl[nt] = B1l[(ntg * 8) * 64 + lane];
  }

  __syncthreads();              // all waves done reading X (H1 aliases it)
  #pragma unroll
  for (int nt = 0; nt < 4; ++nt) {
    int col = (wv * 4 + nt) * 16 + lm;
    float bias = b0[col];
    #pragma unroll
    for (int mt = 0; mt < 4; ++mt)
      #pragma unroll
      for (int reg = 0; reg < 4; ++reg) {
        int row = mt * 16 + lq * 4 + reg;
        H[row * SH + col] = (_Float16)silu_f(acc[mt][nt][reg] + bias);
      }
  }
  __syncthreads();

  // ---- layer 2: K=256 (8 ksteps), B double-buffered ----
  #pragma unroll
  for (int mt = 0; mt < 4; ++mt)
    #pragma unroll
    for (int nt = 0; nt < 4; ++nt) acc[mt][nt] = (floatx4){0.f,0.f,0.f,0.f};
  #pragma unroll
  for (int ks = 0; ks < 8; ++ks) {
    if (ks < 7) {
      #pragma unroll
      for (int nt = 0; nt < 4; ++nt) {
        int ntg = wv * 4 + nt;
        Bhn[nt] = B1h[(ntg * 8 + ks + 1) * 64 + lane];
        Bln[nt] = B1l[(ntg * 8 + ks + 1) * 64 + lane];
      }
    }
    half8 A[4];
    #pragma unroll
    for (int mt = 0; mt < 4; ++mt)
      A[mt] = *(const half8*)&H[(mt * 16 + lm) * SH + ks * 32 + lq * 8];
    __builtin_amdgcn_s_setprio(1);
    #pragma unroll
    for (int mt = 0; mt < 4; ++mt)
      #pragma unroll
      for (int nt = 0; nt < 4; ++nt)
        acc[mt][nt] = __builtin_amdgcn_mfma_f32_16x16x32_f16(A[mt], Bh[nt], acc[mt][nt], 0, 0, 0);
    #pragma unroll
    for (int mt = 0; mt < 4; ++mt)
      #pragma unroll
      for (int nt = 0; nt < 4; ++nt)
        acc[mt][nt] = __builtin_amdgcn_mfma_f32_16x16x32_f16(A[mt], Bl[nt], acc[mt][nt], 0, 0, 0);
    __builtin_amdgcn_s_setprio(0);
    if (ks < 7) {
      #pragma unroll
      for (int nt = 0; nt < 4; ++nt) { Bh[nt] = Bhn[nt]; Bl[nt] = Bln[nt]; }
    }
  }

  // ---- prefetch ALL L3 B fragments before the epilogue barrier ----
  const half8* B2h = (const half8*)(frag + FR_W2P_HI);
  const half8* B2l = (const half8*)(frag + FR_W2P_LO);
  half8 B2hr[8], B2lr[8];
  #pragma unroll
  for (int ks = 0; ks < 8; ++ks) {
    B2hr[ks] = B2h[ks * 64 + lane];
    B2lr[ks] = B2l[ks * 64 + lane];
  }

  __syncthreads();              // all waves done reading H1
  #pragma unroll
  for (int nt = 0; nt < 4; ++nt) {
    int col = (wv * 4 + nt) * 16 + lm;
    float bias = b1[col];
    #pragma unroll
    for (int mt = 0; mt < 4; ++mt)
      #pragma unroll
      for (int reg = 0; reg < 4; ++reg) {
        int row = mt * 16 + lq * 4 + reg;
        H[row * SH + col] = (_Float16)silu_f(acc[mt][nt][reg] + bias);
      }
  }
  __syncthreads();

  // ---- layer 3: N=16, K=256; wave wv handles mtile wv ----
  {
    floatx4 c3a = (floatx4){0.f,0.f,0.f,0.f};
    floatx4 c3b = (floatx4){0.f,0.f,0.f,0.f};
    __builtin_amdgcn_s_setprio(1);
    #pragma unroll
    for (int ks = 0; ks < 8; ks += 2) {
      half8 A0 = *(const half8*)&H[(wv * 16 + lm) * SH + ks * 32 + lq * 8];
      half8 A1 = *(const half8*)&H[(wv * 16 + lm) * SH + (ks + 1) * 32 + lq * 8];
      c3a = __builtin_amdgcn_mfma_f32_16x16x32_f16(A0, B2hr[ks],     c3a, 0, 0, 0);
      c3b = __builtin_amdgcn_mfma_f32_16x16x32_f16(A1, B2hr[ks + 1], c3b, 0, 0, 0);
      c3a = __builtin_amdgcn_mfma_f32_16x16x32_f16(A0, B2lr[ks],     c3a, 0, 0, 0);
      c3b = __builtin_amdgcn_mfma_f32_16x16x32_f16(A1, B2lr[ks + 1], c3b, 0, 0, 0);
    }
    __builtin_amdgcn_s_setprio(0);
    float bias = b2[lm];
    #pragma unroll
    for (int reg = 0; reg < 4; ++reg)
      OUTT[(wv * 16 + lq * 4 + reg) * 16 + lm] = c3a[reg] + c3b[reg] + bias;
  }
  __syncthreads();

  // ---- epilogue: parallel over (row, d): tid = r*8 + d ----
  {
    int r = tid >> 3;          // 0..31
    int d = tid & 7;
    long row = row0 + r;

    float gl  = OUTT[r * 16 + d];
    float gsr = OUTT[r * 16 + 8 + d];
    float ll  = OUTT[(32 + r) * 16 + d];
    float lsr = OUTT[(32 + r) * 16 + 8 + d];
    float a   = action[row * 8 + d];
    float loc = logits[row * 16 + d];
    float sr  = logits[row * 16 + 8 + d];
    float nd  = noise[row * 8 + d];

    float gs = softplus_f(gsr) + 1e-3f;
    float ls = softplus_f(lsr) + 1e-3f;
    float sc = softplus_f(sr) + 1e-3f;
    float ldj = 2.f * (LOG2C_ - a - softplus_f(-2.f * a));
    float lgs = logf(gs), lls = logf(ls), lsc = logf(sc);
    float zg = (a - gl) / gs;
    float zl = (a - ll) / ls;
    float z  = (a - loc) / sc;
    float glp = -0.5f * zg * zg - lgs - HLOG2PI_ - ldj;
    float llp = -0.5f * zl * zl - lls - HLOG2PI_ - ldj;
    float blp = -0.5f * z * z - lsc - HLOG2PI_ - ldj;
    float ratio = gs / ls;
    float vr = ratio * ratio;
    float t1 = (gl - ll) / ls; t1 *= t1;
    float kl = 0.5f * (vr + t1 - 1.f) - (lgs - lls);
    float dist = loc + sc * nd;
    float ent = 0.5f + HLOG2PI_ + lsc
              + 2.f * (LOG2C_ - dist - softplus_f(-2.f * dist));

    // reduce over d (8 adjacent lanes)
    #pragma unroll
    for (int o = 4; o > 0; o >>= 1) {
      glp += __shfl_down(glp, o, 8);
      llp += __shfl_down(llp, o, 8);
      blp += __shfl_down(blp, o, 8);
      kl  += __shfl_down(kl, o, 8);
      ent += __shfl_down(ent, o, 8);
    }

    if (d == 0) {
      kl *= 0.125f;
      kl  = clamp30(kl);
      ent = clamp30(ent);

      float diff = glp - llp;
      float m = (diff > LOG1P2_ || diff < LOG0P8_) ? 1.f : 0.f;

      float N = (float)ROWS_P;
      float sum = accum[3], sumsq = accum[4];
      float mean = sum / N;
      float var  = fmaxf((sumsq - sum * sum / N) / (N - 1.f), 0.f);
      float inv  = 1.f / (sqrtf(var) + 1e-5f);
      float a_n  = (adv[row] - mean) * inv;

      float rho = expf(fminf(glp - blp, 80.f));
      float cl  = fminf(LOG1P2_, fmaxf(LOG0P8_, diff));
      float rc  = expf(fminf(cl + llp - blp, 80.f));
      rc = fminf(1.f + EPSILON_, fmaxf(1.f - EPSILON_, rc));
      float gp = clamp30(fminf(rho * a_n, rc * a_n));

      float rho2 = expf(fminf(llp - blp, 10.f));
      float r2c  = fminf(1.f + EPSILON_, fmaxf(1.f - EPSILON_, rho2));
      float lp = clamp30(fminf(rho2 * a_n, r2c * a_n));

      red[r]       = kl;
      red[32 + r]  = kl * m;
      red[64 + r]  = ent;
      red[96 + r]  = gp;
      red[128 + r] = lp;
    }
  }
  __syncthreads();
  if (tid < 32) {
    float s0 = red[tid], s1 = red[32 + tid], s2 = red[64 + tid];
    float s3 = red[96 + tid], s4 = red[128 + tid];
    #pragma unroll
    for (int o = 16; o > 0; o >>= 1) {
      s0 += __shfl_down(s0, o, 32);
      s1 += __shfl_down(s1, o, 32);
      s2 += __shfl_down(s2, o, 32);
      s3 += __shfl_down(s3, o, 32);
      s4 += __shfl_down(s4, o, 32);
    }
    if (tid == 0) {
      atomicAdd(&accum[0], s0);
      atomicAdd(&accum[1], s1);
      atomicAdd(&accum[2], s2);
      atomicAdd(&accum[6], s3);
      atomicAdd(&accum[7], s4);
    }
  }
}

// =====================================================================
// Value: block = 64 obs rows, same structure; layer3 W2 zero-padded to
// 16 wide (only n=0 valid); baseline = col 0.
// =====================================================================
__global__ __launch_bounds__(256, 4)
void value_kernel(const float* __restrict__ obs,
                  const float* __restrict__ rm,
                  const float* __restrict__ inv_std,
                  const u16* __restrict__ frag,
                  const float* __restrict__ b0,
                  const float* __restrict__ b1,
                  const float* __restrict__ b2,
                  float* __restrict__ baseline) {
  __shared__ __align__(16) _Float16 H[64 * SH];
  __shared__ float OUTT[64 * 16];

  const int tid  = threadIdx.x;
  const long row0 = (long)blockIdx.x * 64;
  const int lane = tid & 63;
  const int wv   = tid >> 6;
  const int lm   = lane & 15;
  const int lq   = lane >> 4;

  _Float16* X = H;

  #pragma unroll
  for (int it = 0; it < 2; ++it) {
    int flat = it * 256 + tid;
    int vr = flat >> 3;
    int f0 = (flat & 7) * 8;
    floatx8 v  = *(const floatx8*)&obs[(row0 + vr) * 64 + f0];
    floatx8 m  = *(const floatx8*)&rm[f0];
    floatx8 is = *(const floatx8*)&inv_std[f0];
    half8 h;
    #pragma unroll
    for (int j = 0; j < 8; ++j)
      h[j] = (_Float16)fminf(5.f, fmaxf(-5.f, (v[j] - m[j]) * is[j]));
    *(half8*)&X[vr * SX + f0] = h;
  }

  // ---- prefetch L1 B fragments ----
  const half8* B0h = (const half8*)(frag + FR_W0V_HI);
  const half8* B0l = (const half8*)(frag + FR_W0V_LO);
  half8 B0hr[2][4], B0lr[2][4];
  #pragma unroll
  for (int ks = 0; ks < 2; ++ks)
    #pragma unroll
    for (int nt = 0; nt < 4; ++nt) {
      int ntg = wv * 4 + nt;
      B0hr[ks][nt] = B0h[(ntg * 2 + ks) * 64 + lane];
      B0lr[ks][nt] = B0l[(ntg * 2 + ks) * 64 + lane];
    }
  __syncthreads();

  floatx4 acc[4][4];

  #pragma unroll
  for (int mt = 0; mt < 4; ++mt)
    #pragma unroll
    for (int nt = 0; nt < 4; ++nt) acc[mt][nt] = (floatx4){0.f,0.f,0.f,0.f};
  #pragma unroll
  for (int ks = 0; ks < 2; ++ks) {
    half8 A[4];
    #pragma unroll
    for (int mt = 0; mt < 4; ++mt)
      A[mt] = *(const half8*)&X[(mt * 16 + lm) * SX + ks * 32 + lq * 8];
    __builtin_amdgcn_s_setprio(1);
    #pragma unroll
    for (int mt = 0; mt < 4; ++mt)
      #pragma unroll
      for (int nt = 0; nt < 4; ++nt)
        acc[mt][nt] = __builtin_amdgcn_mfma_f32_16x16x32_f16(A[mt], B0hr[ks][nt], acc[mt][nt], 0, 0, 0);
    #pragma unroll
    for (int mt = 0; mt < 4; ++mt)
      #pragma unroll
      for (int nt = 0; nt < 4; ++nt)
        acc[mt][nt] = __builtin_amdgcn_mfma_f32_16x16x32_f16(A[mt], B0lr[ks][nt], acc[mt][nt], 0, 0, 0);
    __builtin_amdgcn_s_setprio(0);
  }

  // ---- prefetch L2 ks=0 B fragments ----
  const half8* B1h = (const half8*)(frag + FR_W1V_HI);
  const half8* B1l = (const half8*)(frag + FR_W1V_LO);
  half8 Bh[4], Bl[4], Bhn[4], Bln[4];
  #pragma unroll
  for (int nt = 0; nt < 4; ++nt) {
    int ntg = wv * 4 + nt;
    Bh[nt] = B1h[(ntg * 8) * 64 + lane];
    Bl[nt] = B1l[(ntg * 8) * 64 + lane];
  }

  __syncthreads();
  #pragma unroll
  for (int nt = 0; nt < 4; ++nt) {
    int col = (wv * 4 + nt) * 16 + lm;
    float bias = b0[col];
    #pragma unroll
    for (int mt = 0; mt < 4; ++mt)
      #pragma unroll
      for (int reg = 0; reg < 4; ++reg) {
        int row = mt * 16 + lq * 4 + reg;
        H[row * SH + col] = (_Float16)silu_f(acc[mt][nt][reg] + bias);
      }
  }
  __syncthreads();

  #pragma unroll
  for (int mt = 0; mt < 4; ++mt)
    #pragma unroll
    for (int nt = 0; nt < 4; ++nt) acc[mt][nt] = (floatx4){0.f,0.f,0.f,0.f};
  #pragma unroll
  for (int ks = 0; ks < 8; ++ks) {
    if (ks < 7) {
      #pragma unroll
      for (int nt = 0; nt < 4; ++nt) {
        int ntg = wv * 4 + nt;
        Bhn[nt] = B1h[(ntg * 8 + ks + 1) * 64 + lane];
        Bln[nt] = B1l[(ntg * 8 + ks + 1) * 64 + lane];
      }
    }
    half8 A[4];
    #pragma unroll
    for (int mt = 0; mt < 4; ++mt)
      A[mt] = *(const half8*)&H[(mt * 16 + lm) * SH + ks * 32 + lq * 8];
    __builtin_amdgcn_s_setprio(1);
    #pragma unroll
    for (int mt = 0; mt < 4; ++mt)
      #pragma unroll
      for (int nt = 0; nt < 4; ++nt)
        acc[mt][nt] = __builtin_amdgcn_mfma_f32_16x16x32_f16(A[mt], Bh[nt], acc[mt][nt], 0, 0, 0);
    #pragma unroll
    for (int mt = 0; mt < 4; ++mt)
      #pragma unroll
      for (int nt = 0; nt < 4; ++nt)
        acc[mt][nt] = __builtin_amdgcn_mfma_f32_16x16x32_f16(A[mt], Bl[nt], acc[mt][nt], 0, 0, 0);
    __builtin_amdgcn_s_setprio(0);
    if (ks < 7) {
      #pragma unroll
      for (int nt = 0; nt < 4; ++nt) { Bh[nt] = Bhn[nt]; Bl[nt] = Bln[nt]; }
    }
  }

  // ---- prefetch ALL L3 B fragments ----
  const half8* B2h = (const half8*)(frag + FR_W2V_HI);
  const half8* B2l = (const half8*)(frag + FR_W2V_LO);
  half8 B2hr[8], B2lr[8];
  #pragma unroll
  for (int ks = 0; ks < 8; ++ks) {
    B2hr[ks] = B2h[ks * 64 + lane];
    B2lr[ks] = B2l[ks * 64 + lane];
  }

  __syncthreads();
  #pragma unroll
  for (int nt = 0; nt < 4; ++nt) {
    int col = (wv * 4 + nt) * 16 + lm;
    float bias = b1[col];
    #pragma unroll
    for (int mt = 0; mt < 4; ++mt)
      #pragma unroll
      for (int reg = 0; reg < 4; ++reg) {
        int row = mt * 16 + lq * 4 + reg;
        H[row * SH + col] = (_Float16)silu_f(acc[mt][nt][reg] + bias);
      }
  }
  __syncthreads();

  {
    floatx4 c3a = (floatx4){0.f,0.f,0.f,0.f};
    floatx4 c3b = (floatx4){0.f,0.f,0.f,0.f};
    __builtin_amdgcn_s_setprio(1);
    #pragma unroll
    for (int ks = 0; ks < 8; ks += 2) {
      half8 A0 = *(const half8*)&H[(wv * 16 + lm) * SH + ks * 32 + lq * 8];
      half8 A1 = *(const half8*)&H[(wv * 16 + lm) * SH + (ks + 1) * 32 + lq * 8];
      c3a = __builtin_amdgcn_mfma_f32_16x16x32_f16(A0, B2hr[ks],     c3a, 0, 0, 0);
      c3b = __builtin_amdgcn_mfma_f32_16x16x32_f16(A1, B2hr[ks + 1], c3b, 0, 0, 0);
      c3a = __builtin_amdgcn_mfma_f32_16x16x32_f16(A0, B2lr[ks],     c3a, 0, 0, 0);
      c3b = __builtin_amdgcn_mfma_f32_16x16x32_f16(A1, B2lr[ks + 1], c3b, 0, 0, 0);
    }
    __builtin_amdgcn_s_setprio(0);
    #pragma unroll
    for (int reg = 0; reg < 4; ++reg)
      OUTT[(wv * 16 + lq * 4 + reg) * 16 + lm] = c3a[reg] + c3b[reg];
  }
  __syncthreads();

  if (tid < 64) baseline[row0 + tid] = OUTT[tid * 16] + b2[0];
}

// ---------------- GAE segmented scan (unchanged, verified) ----------------
__global__ void gae_phase1(const float* __restrict__ reward,
                           const float* __restrict__ done,
                           const float* __restrict__ trunc,
                           const float* __restrict__ baseline,
                           float* __restrict__ A, float* __restrict__ P) {
  int s = blockIdx.x, b = threadIdx.x;
  float Aa = 0.f, Pp = 1.f;
  for (int t = (s + 1) * 32 - 1; t >= s * 32; --t) {
    int idx = t * 256 + b;
    float r = reward[idx], d = done[idx], tr = trunc[idx];
    float tm = 1.f - tr;
    float te = d * tm;
    float bl = baseline[idx], bl1 = baseline[idx + 256];
    float g1 = GAMMA_ * (1.f - te);
    float delta = (r + g1 * bl1 - bl) * tm;
    float c = g1 * tm * LAM_;
    Aa = delta + c * Aa;
    Pp = c * Pp;
  }
  A[s * 256 + b] = Aa;
  P[s * 256 + b] = Pp;
}

__global__ void gae_phase2(const float* __restrict__ A,
                           const float* __restrict__ P,
                           float* __restrict__ seedv) {
  int b = threadIdx.x;
  float acc = 0.f;
  for (int s = 31; s >= 0; --s) {
    seedv[s * 256 + b] = acc;
    acc = A[s * 256 + b] + P[s * 256 + b] * acc;
  }
}

__global__ void gae_phase3(const float* __restrict__ reward,
                           const float* __restrict__ done,
                           const float* __restrict__ trunc,
                           const float* __restrict__ baseline,
                           const float* __restrict__ seedv,
                           float* __restrict__ adv,
                           float* __restrict__ accum) {
  __shared__ float red[12];
  int s = blockIdx.x, b = threadIdx.x;
  float acc = seedv[s * 256 + b];
  int tend = (s + 1) * 32;
  float vnext = baseline[tend * 256 + b];
  float vs_next = acc + vnext;
  float sa = 0.f, sa2 = 0.f, sv2 = 0.f;
  for (int t = tend - 1; t >= s * 32; --t) {
    int idx = t * 256 + b;
    float r = reward[idx], d = done[idx], tr = trunc[idx];
    float tm = 1.f - tr;
    float te = d * tm;
    float bl = baseline[idx];
    float g1 = GAMMA_ * (1.f - te);
    float delta = (r + g1 * vnext - bl) * tm;
    acc = delta + g1 * tm * LAM_ * acc;
    float at = (r + g1 * vs_next - bl) * tm;
    at = fminf(1e15f, fmaxf(-1e15f, at));
    adv[idx] = at;
    sa += at; sa2 += at * at;
    sv2 += fminf(acc * acc, 1e30f);
    vs_next = acc + bl;
    vnext = bl;
  }
  float v0 = sa, v1 = sa2, v2 = sv2;
  #pragma unroll
  for (int o = 32; o > 0; o >>= 1) {
    v0 += __shfl_down(v0, o, 64);
    v1 += __shfl_down(v1, o, 64);
    v2 += __shfl_down(v2, o, 64);
  }
  int lane = threadIdx.x & 63, w = threadIdx.x >> 6;
  if (lane == 0) { red[w] = v0; red[4 + w] = v1; red[8 + w] = v2; }
  __syncthreads();
  if (threadIdx.x == 0) {
    float s0=0.f, s1=0.f, s2=0.f;
    for (int q = 0; q < 4; ++q) { s0 += red[q]; s1 += red[4+q]; s2 += red[8+q]; }
    atomicAdd(&accum[3], s0);
    atomicAdd(&accum[4], s1);
    atomicAdd(&accum[5], s2);
  }
}

// ---------------- finalize ----------------
__global__ void finalize_kernel(const float* __restrict__ accum,
                                float* __restrict__ out) {
  float N = (float)ROWS_P;
  float kl_learner = accum[0] / N;
  float kl_guider  = accum[1] / N;
  float entropy    = accum[2] / N;
  float v_loss     = 0.25f * accum[5] / N;
  float gp_loss    = -accum[6] / N;
  float lp_loss    = -accum[7] / N;
  float learner_loss = kl_learner + lp_loss;      // ALPHA = 1
  float guider_loss  = kl_guider + gp_loss;
  float total = learner_loss + guider_loss + v_loss - 0.01f * entropy;
  out[0] = total;
  out[1] = guider_loss;
  out[2] = learner_loss;
  out[3] = kl_learner;
}

extern "C" void kernel_launch(void* const* d_in, const int* in_sizes, int n_in,
                              void* d_out, int out_size, void* d_ws, size_t ws_size,
                              hipStream_t stream) {
  (void)in_sizes; (void)n_in; (void)out_size; (void)ws_size;
  const float* obs    = (const float*)d_in[0];
  const float* pobs   = (const float*)d_in[1];
  const float* reward = (const float*)d_in[2];
  const float* done   = (const float*)d_in[3];
  const float* trunc  = (const float*)d_in[4];
  const float* logits = (const float*)d_in[5];
  const float* action = (const float*)d_in[6];
  const float* noise  = (const float*)d_in[7];
  const float* pw0 = (const float*)d_in[8];
  const float* pb0 = (const float*)d_in[9];
  const float* pw1 = (const float*)d_in[10];
  const float* pb1 = (const float*)d_in[11];
  const float* pw2 = (const float*)d_in[12];
  const float* pb2 = (const float*)d_in[13];
  const float* vw0 = (const float*)d_in[14];
  const float* vb0 = (const float*)d_in[15];
  const float* vw1 = (const float*)d_in[16];
  const float* vb1 = (const float*)d_in[17];
  const float* vw2 = (const float*)d_in[18];
  const float* vb2 = (const float*)d_in[19];
  const float* rm  = (const float*)d_in[20];
  const float* rv  = (const float*)d_in[21];

  u16*   frag  = (u16*)d_ws;
  float* fbase = (float*)d_ws + FR_TOTAL / 2;
  float* accum   = fbase + WS_ACC;
  float* inv_std = fbase + WS_INV;
  float* adv     = fbase + WS_ADV;
  float* base    = fbase + WS_BASE;
  float* gA      = fbase + WS_GA;
  float* gP      = fbase + WS_GP;
  float* gS      = fbase + WS_GS;
  float* out = (float*)d_out;

  prep_kernel<<<1, 256, 0, stream>>>(rv, inv_std, accum);
  convert_kernel<<<672, 256, 0, stream>>>(pw0, pw1, pw2, vw0, vw1, vw2, frag);

  value_kernel<<<(int)(ROWS_V / 64), 256, 0, stream>>>(
      obs, rm, inv_std, frag, vb0, vb1, vb2, base);

  gae_phase1<<<32, 256, 0, stream>>>(reward, done, trunc, base, gA, gP);
  gae_phase2<<<1, 256, 0, stream>>>(gA, gP, gS);
  gae_phase3<<<32, 256, 0, stream>>>(reward, done, trunc, base, gS, adv, accum);

  policy_kernel<<<(int)(ROWS_P / 32), 256, 0, stream>>>(
      obs, pobs, rm, inv_std, frag, pb0, pb1, pb2,
      logits, action, noise, adv, accum);

  finalize_kernel<<<1, 1, 0, stream>>>(accum, out);
}

// Round 3
// 812.738 us; speedup vs baseline: 1.6890x; 1.6890x over previous
//
#include <hip/hip_runtime.h>
#include <math.h>

#define GAMMA_   0.97f
#define LAM_     0.95f
#define EPSILON_ 0.3f
#define HLOG2PI_ 0.91893853320467274f
#define LOG2C_   0.69314718055994531f
#define LOG1P2_  0.18232155679395463f
#define LOG0P8_  (-0.22314355131420976f)

typedef unsigned short u16;
typedef unsigned int   u32;
typedef _Float16 half8 __attribute__((ext_vector_type(8)));
typedef _Float16 half4 __attribute__((ext_vector_type(4)));
typedef __attribute__((ext_vector_type(4))) float floatx4;
typedef __attribute__((ext_vector_type(8))) float floatx8;

constexpr int  TT     = 1024;
constexpr long ROWS_P = (long)TT * 256;          // 262144
constexpr long ROWS_V = (long)(TT + 1) * 256;    // 262400

// ---- fragment workspace layout (u16 offsets from ws base) ----
constexpr long FR_W0P_HI = 0;        // NT16 KS2  -> 16384
constexpr long FR_W0P_LO = 16384;
constexpr long FR_W1P_HI = 32768;    // NT16 KS8  -> 65536
constexpr long FR_W1P_LO = 98304;
constexpr long FR_W2P_HI = 163840;   // NT1  KS8  -> 4096
constexpr long FR_W2P_LO = 167936;
constexpr long FR_W0V_HI = 172032;
constexpr long FR_W0V_LO = 188416;
constexpr long FR_W1V_HI = 204800;
constexpr long FR_W1V_LO = 270336;
constexpr long FR_W2V_HI = 335872;
constexpr long FR_W2V_LO = 339968;
constexpr long FR_TOTAL  = 344064;   // u16 elems

// ---- float workspace (offsets from (float*)ws + FR_TOTAL/2) ----
constexpr long WS_ACC  = 0;                 // 32
constexpr long WS_INV  = 32;                // 64
constexpr long WS_ADV  = 96;                // 262144
constexpr long WS_BASE = WS_ADV + ROWS_P;   // 262400
constexpr long WS_GA   = WS_BASE + ROWS_V;  // 8192
constexpr long WS_GP   = WS_GA + 8192;
constexpr long WS_GS   = WS_GP + 8192;

// accum slots: 0 kl_sum, 1 kl_m_sum, 2 ent_sum, 3 adv_sum, 4 adv2_sum,
//              5 vmx2_sum, 6 gp_sum, 7 lp_sum

__device__ __forceinline__ float softplus_f(float x) {
  return (x > 20.f) ? x : log1pf(expf(x));
}
// silu: result is truncated to fp16 downstream, so v_rcp_f32 (~2^-22 rel err)
// is exact at the storage precision and saves the precise-div sequence.
__device__ __forceinline__ float silu_f(float x) {
  return x * __builtin_amdgcn_rcpf(1.f + __expf(-x));
}
__device__ __forceinline__ float clamp30(float x) {
  return fminf(1e30f, fmaxf(-1e30f, x));
}

// ---------------- prep ----------------
__global__ void prep_kernel(const float* __restrict__ rv,
                            float* __restrict__ inv_std,
                            float* __restrict__ accum) {
  int t = threadIdx.x;
  if (t < 32) accum[t] = 0.f;
  if (t < 64) {
    float var = rv[t] / 1000001.0f;
    var = fminf(1e6f, fmaxf(1e-6f, var));
    inv_std[t] = 1.f / sqrtf(var);
  }
}

// ---------------- weight -> split-fp16 MFMA fragments ----------------
__global__ void convert_kernel(const float* __restrict__ pw0,
                               const float* __restrict__ pw1,
                               const float* __restrict__ pw2,
                               const float* __restrict__ vw0,
                               const float* __restrict__ vw1,
                               const float* __restrict__ vw2,
                               u16* __restrict__ frag) {
  int idx = blockIdx.x * 256 + threadIdx.x;   // 0..172031
  const float* W; int kslog, K, nvalid; long hioff, looff; int e;
  if (idx < 16384)       { W = pw0; e = idx;          kslog = 1; K = 64;  nvalid = 256; hioff = FR_W0P_HI; looff = FR_W0P_LO; }
  else if (idx < 81920)  { W = pw1; e = idx - 16384;  kslog = 3; K = 256; nvalid = 256; hioff = FR_W1P_HI; looff = FR_W1P_LO; }
  else if (idx < 86016)  { W = pw2; e = idx - 81920;  kslog = 3; K = 256; nvalid = 16;  hioff = FR_W2P_HI; looff = FR_W2P_LO; }
  else if (idx < 102400) { W = vw0; e = idx - 86016;  kslog = 1; K = 64;  nvalid = 256; hioff = FR_W0V_HI; looff = FR_W0V_LO; }
  else if (idx < 167936) { W = vw1; e = idx - 102400; kslog = 3; K = 256; nvalid = 256; hioff = FR_W1V_HI; looff = FR_W1V_LO; }
  else                   { W = vw2; e = idx - 167936; kslog = 3; K = 256; nvalid = 1;   hioff = FR_W2V_HI; looff = FR_W2V_LO; }
  int j    = e & 7;
  int lane = (e >> 3) & 63;
  int ks   = (e >> 9) & ((1 << kslog) - 1);
  int nt   = e >> (9 + kslog);
  int n = nt * 16 + (lane & 15);
  int k = ks * 32 + ((lane >> 4) << 3) + j;
  float w = (n < nvalid) ? W[n * K + k] : 0.f;
  _Float16 hi = (_Float16)w;
  _Float16 lo = (_Float16)(w - (float)hi);
  frag[hioff + e] = *(u16*)&hi;
  frag[looff + e] = *(u16*)&lo;
}

// LDS strides (fp16 units); multiples of 8 (16B-aligned rows)
constexpr int SX = 72;    // X row stride
constexpr int SH = 264;   // H row stride

// =====================================================================
// Policy: block = 32 obs rows (vrows 0..31) + same 32 pobs rows (32..63).
// 4 waves; wave wv owns ntile quarter (4 ntiles = 64 cols) x ALL 4 mtiles.
// This revision: MFMA operands SWAPPED (W as A, X as B) so D = W*X^T:
// a thread's 4 acc regs = 4 consecutive FEATURES of one row -> packed
// ds_write_b64 epilogues (16 writes/layer vs 64 scattered b16).
// launch_bounds back to (256,3): (256,4) forced 64 VGPR + spills (R2: 3GB
// scratch traffic, 849us).
// =====================================================================
__global__ __launch_bounds__(256, 3)
void policy_kernel(const float* __restrict__ obs,
                   const float* __restrict__ pobs,
                   const float* __restrict__ rm,
                   const float* __restrict__ inv_std,
                   const u16* __restrict__ frag,
                   const float* __restrict__ b0,
                   const float* __restrict__ b1,
                   const float* __restrict__ b2,
                   const float* __restrict__ logits,
                   const float* __restrict__ action,
                   const float* __restrict__ noise,
                   const float* __restrict__ adv,
                   float* __restrict__ accum) {
  __shared__ __align__(16) _Float16 H[64 * SH];   // 33792 B, X aliases in
  __shared__ __align__(16) float OUTT[64 * 16];
  __shared__ float red[160];

  const int tid  = threadIdx.x;
  const long row0 = (long)blockIdx.x * 32;
  const int lane = tid & 63;
  const int wv   = tid >> 6;         // ntile quarter
  const int lm   = lane & 15;
  const int lq   = lane >> 4;

  _Float16* X = H;                   // X dead after L1 MFMA

  // ---- stage normalized X (vrows 0..31 obs, 32..63 pobs), vectorized ----
  #pragma unroll
  for (int it = 0; it < 2; ++it) {
    int flat = it * 256 + tid;       // 512 groups of 8 floats
    int vr = flat >> 3;
    int f0 = (flat & 7) * 8;
    const float* src = (vr < 32) ? obs : pobs;
    floatx8 v  = *(const floatx8*)&src[(row0 + (vr & 31)) * 64 + f0];
    floatx8 m  = *(const floatx8*)&rm[f0];
    floatx8 is = *(const floatx8*)&inv_std[f0];
    half8 h;
    #pragma unroll
    for (int j = 0; j < 8; ++j)
      h[j] = (_Float16)fminf(5.f, fmaxf(-5.f, (v[j] - m[j]) * is[j]));
    *(half8*)&X[vr * SX + f0] = h;
  }

  // ---- prefetch L1 B fragments (global only, safe across barrier) ----
  const half8* B0h = (const half8*)(frag + FR_W0P_HI);
  const half8* B0l = (const half8*)(frag + FR_W0P_LO);
  half8 B0hr[2][4], B0lr[2][4];
  #pragma unroll
  for (int ks = 0; ks < 2; ++ks)
    #pragma unroll
    for (int nt = 0; nt < 4; ++nt) {
      int ntg = wv * 4 + nt;
      B0hr[ks][nt] = B0h[(ntg * 2 + ks) * 64 + lane];
      B0lr[ks][nt] = B0l[(ntg * 2 + ks) * 64 + lane];
    }
  __syncthreads();

  floatx4 acc[4][4];

  // ---- layer 1: K=64 (2 ksteps); D = W*X^T (swapped operands) ----
  #pragma unroll
  for (int mt = 0; mt < 4; ++mt)
    #pragma unroll
    for (int nt = 0; nt < 4; ++nt) acc[mt][nt] = (floatx4){0.f,0.f,0.f,0.f};
  #pragma unroll
  for (int ks = 0; ks < 2; ++ks) {
    half8 A[4];
    #pragma unroll
    for (int mt = 0; mt < 4; ++mt)
      A[mt] = *(const half8*)&X[(mt * 16 + lm) * SX + ks * 32 + lq * 8];
    __builtin_amdgcn_s_setprio(1);
    #pragma unroll
    for (int mt = 0; mt < 4; ++mt)
      #pragma unroll
      for (int nt = 0; nt < 4; ++nt)
        acc[mt][nt] = __builtin_amdgcn_mfma_f32_16x16x32_f16(B0hr[ks][nt], A[mt], acc[mt][nt], 0, 0, 0);
    #pragma unroll
    for (int mt = 0; mt < 4; ++mt)
      #pragma unroll
      for (int nt = 0; nt < 4; ++nt)
        acc[mt][nt] = __builtin_amdgcn_mfma_f32_16x16x32_f16(B0lr[ks][nt], A[mt], acc[mt][nt], 0, 0, 0);
    __builtin_amdgcn_s_setprio(0);
  }

  // ---- prefetch L2 ks=0 B fragments before the epilogue barrier ----
  const half8* B1h = (const half8*)(frag + FR_W1P_HI);
  const half8* B1l = (const half8*)(frag + FR_W1P_LO);
  half8 Bh[4], Bl[4], Bhn[4], Bln[4];
  #pragma unroll
  for (int nt = 0; nt < 4; ++nt) {
    int ntg = wv * 4 + nt;
    Bh[nt] = B1h[(ntg * 8) * 64 + lane];
    Bl[nt] = B1l[(ntg * 8) * 64 + lane];
  }

  __syncthreads();              // all waves done reading X (H1 aliases it)
  // acc[mt][nt][reg]: row = mt*16+lm, feature = (wv*4+nt)*16 + lq*4 + reg
  #pragma unroll
  for (int nt = 0; nt < 4; ++nt) {
    int colbase = (wv * 4 + nt) * 16 + lq * 4;
    floatx4 bias = *(const floatx4*)&b0[colbase];
    #pragma unroll
    for (int mt = 0; mt < 4; ++mt) {
      int row = mt * 16 + lm;
      half4 h;
      #pragma unroll
      for (int reg = 0; reg < 4; ++reg)
        h[reg] = (_Float16)silu_f(acc[mt][nt][reg] + bias[reg]);
      *(half4*)&H[row * SH + colbase] = h;
    }
  }
  __syncthreads();

  // ---- layer 2: K=256 (8 ksteps), B double-buffered ----
  #pragma unroll
  for (int mt = 0; mt < 4; ++mt)
    #pragma unroll
    for (int nt = 0; nt < 4; ++nt) acc[mt][nt] = (floatx4){0.f,0.f,0.f,0.f};
  #pragma unroll
  for (int ks = 0; ks < 8; ++ks) {
    if (ks < 7) {
      #pragma unroll
      for (int nt = 0; nt < 4; ++nt) {
        int ntg = wv * 4 + nt;
        Bhn[nt] = B1h[(ntg * 8 + ks + 1) * 64 + lane];
        Bln[nt] = B1l[(ntg * 8 + ks + 1) * 64 + lane];
      }
    }
    half8 A[4];
    #pragma unroll
    for (int mt = 0; mt < 4; ++mt)
      A[mt] = *(const half8*)&H[(mt * 16 + lm) * SH + ks * 32 + lq * 8];
    __builtin_amdgcn_s_setprio(1);
    #pragma unroll
    for (int mt = 0; mt < 4; ++mt)
      #pragma unroll
      for (int nt = 0; nt < 4; ++nt)
        acc[mt][nt] = __builtin_amdgcn_mfma_f32_16x16x32_f16(Bh[nt], A[mt], acc[mt][nt], 0, 0, 0);
    #pragma unroll
    for (int mt = 0; mt < 4; ++mt)
      #pragma unroll
      for (int nt = 0; nt < 4; ++nt)
        acc[mt][nt] = __builtin_amdgcn_mfma_f32_16x16x32_f16(Bl[nt], A[mt], acc[mt][nt], 0, 0, 0);
    __builtin_amdgcn_s_setprio(0);
    if (ks < 7) {
      #pragma unroll
      for (int nt = 0; nt < 4; ++nt) { Bh[nt] = Bhn[nt]; Bl[nt] = Bln[nt]; }
    }
  }

  // ---- prefetch ALL L3 B fragments before the epilogue barrier ----
  const half8* B2h = (const half8*)(frag + FR_W2P_HI);
  const half8* B2l = (const half8*)(frag + FR_W2P_LO);
  half8 B2hr[8], B2lr[8];
  #pragma unroll
  for (int ks = 0; ks < 8; ++ks) {
    B2hr[ks] = B2h[ks * 64 + lane];
    B2lr[ks] = B2l[ks * 64 + lane];
  }

  __syncthreads();              // all waves done reading H1
  #pragma unroll
  for (int nt = 0; nt < 4; ++nt) {
    int colbase = (wv * 4 + nt) * 16 + lq * 4;
    floatx4 bias = *(const floatx4*)&b1[colbase];
    #pragma unroll
    for (int mt = 0; mt < 4; ++mt) {
      int row = mt * 16 + lm;
      half4 h;
      #pragma unroll
      for (int reg = 0; reg < 4; ++reg)
        h[reg] = (_Float16)silu_f(acc[mt][nt][reg] + bias[reg]);
      *(half4*)&H[row * SH + colbase] = h;
    }
  }
  __syncthreads();

  // ---- layer 3: N=16, K=256; wave wv handles mtile wv ----
  {
    floatx4 c3a = (floatx4){0.f,0.f,0.f,0.f};
    floatx4 c3b = (floatx4){0.f,0.f,0.f,0.f};
    __builtin_amdgcn_s_setprio(1);
    #pragma unroll
    for (int ks = 0; ks < 8; ks += 2) {
      half8 A0 = *(const half8*)&H[(wv * 16 + lm) * SH + ks * 32 + lq * 8];
      half8 A1 = *(const half8*)&H[(wv * 16 + lm) * SH + (ks + 1) * 32 + lq * 8];
      c3a = __builtin_amdgcn_mfma_f32_16x16x32_f16(B2hr[ks],     A0, c3a, 0, 0, 0);
      c3b = __builtin_amdgcn_mfma_f32_16x16x32_f16(B2hr[ks + 1], A1, c3b, 0, 0, 0);
      c3a = __builtin_amdgcn_mfma_f32_16x16x32_f16(B2lr[ks],     A0, c3a, 0, 0, 0);
      c3b = __builtin_amdgcn_mfma_f32_16x16x32_f16(B2lr[ks + 1], A1, c3b, 0, 0, 0);
    }
    __builtin_amdgcn_s_setprio(0);
    // D[feature][row]: row = wv*16+lm, features = lq*4 + reg (contig)
    floatx4 bias = *(const floatx4*)&b2[lq * 4];
    *(floatx4*)&OUTT[(wv * 16 + lm) * 16 + lq * 4] = c3a + c3b + bias;
  }
  __syncthreads();

  // ---- epilogue: parallel over (row, d): tid = r*8 + d ----
  {
    int r = tid >> 3;          // 0..31
    int d = tid & 7;
    long row = row0 + r;

    float gl  = OUTT[r * 16 + d];
    float gsr = OUTT[r * 16 + 8 + d];
    float ll  = OUTT[(32 + r) * 16 + d];
    float lsr = OUTT[(32 + r) * 16 + 8 + d];
    float a   = action[row * 8 + d];
    float loc = logits[row * 16 + d];
    float sr  = logits[row * 16 + 8 + d];
    float nd  = noise[row * 8 + d];

    float gs = softplus_f(gsr) + 1e-3f;
    float ls = softplus_f(lsr) + 1e-3f;
    float sc = softplus_f(sr) + 1e-3f;
    float ldj = 2.f * (LOG2C_ - a - softplus_f(-2.f * a));
    float lgs = logf(gs), lls = logf(ls), lsc = logf(sc);
    float zg = (a - gl) / gs;
    float zl = (a - ll) / ls;
    float z  = (a - loc) / sc;
    float glp = -0.5f * zg * zg - lgs - HLOG2PI_ - ldj;
    float llp = -0.5f * zl * zl - lls - HLOG2PI_ - ldj;
    float blp = -0.5f * z * z - lsc - HLOG2PI_ - ldj;
    float ratio = gs / ls;
    float vr = ratio * ratio;
    float t1 = (gl - ll) / ls; t1 *= t1;
    float kl = 0.5f * (vr + t1 - 1.f) - (lgs - lls);
    float dist = loc + sc * nd;
    float ent = 0.5f + HLOG2PI_ + lsc
              + 2.f * (LOG2C_ - dist - softplus_f(-2.f * dist));

    // reduce over d (8 adjacent lanes)
    #pragma unroll
    for (int o = 4; o > 0; o >>= 1) {
      glp += __shfl_down(glp, o, 8);
      llp += __shfl_down(llp, o, 8);
      blp += __shfl_down(blp, o, 8);
      kl  += __shfl_down(kl, o, 8);
      ent += __shfl_down(ent, o, 8);
    }

    if (d == 0) {
      kl *= 0.125f;
      kl  = clamp30(kl);
      ent = clamp30(ent);

      float diff = glp - llp;
      float m = (diff > LOG1P2_ || diff < LOG0P8_) ? 1.f : 0.f;

      float N = (float)ROWS_P;
      float sum = accum[3], sumsq = accum[4];
      float mean = sum / N;
      float var  = fmaxf((sumsq - sum * sum / N) / (N - 1.f), 0.f);
      float inv  = 1.f / (sqrtf(var) + 1e-5f);
      float a_n  = (adv[row] - mean) * inv;

      float rho = expf(fminf(glp - blp, 80.f));
      float cl  = fminf(LOG1P2_, fmaxf(LOG0P8_, diff));
      float rc  = expf(fminf(cl + llp - blp, 80.f));
      rc = fminf(1.f + EPSILON_, fmaxf(1.f - EPSILON_, rc));
      float gp = clamp30(fminf(rho * a_n, rc * a_n));

      float rho2 = expf(fminf(llp - blp, 10.f));
      float r2c  = fminf(1.f + EPSILON_, fmaxf(1.f - EPSILON_, rho2));
      float lp = clamp30(fminf(rho2 * a_n, r2c * a_n));

      red[r]       = kl;
      red[32 + r]  = kl * m;
      red[64 + r]  = ent;
      red[96 + r]  = gp;
      red[128 + r] = lp;
    }
  }
  __syncthreads();
  if (tid < 32) {
    float s0 = red[tid], s1 = red[32 + tid], s2 = red[64 + tid];
    float s3 = red[96 + tid], s4 = red[128 + tid];
    #pragma unroll
    for (int o = 16; o > 0; o >>= 1) {
      s0 += __shfl_down(s0, o, 32);
      s1 += __shfl_down(s1, o, 32);
      s2 += __shfl_down(s2, o, 32);
      s3 += __shfl_down(s3, o, 32);
      s4 += __shfl_down(s4, o, 32);
    }
    if (tid == 0) {
      atomicAdd(&accum[0], s0);
      atomicAdd(&accum[1], s1);
      atomicAdd(&accum[2], s2);
      atomicAdd(&accum[6], s3);
      atomicAdd(&accum[7], s4);
    }
  }
}

// =====================================================================
// Value: block = 64 obs rows, same structure; swapped MFMA operands,
// packed epilogues; L3 writes baseline directly from registers (no OUTT).
// =====================================================================
__global__ __launch_bounds__(256, 3)
void value_kernel(const float* __restrict__ obs,
                  const float* __restrict__ rm,
                  const float* __restrict__ inv_std,
                  const u16* __restrict__ frag,
                  const float* __restrict__ b0,
                  const float* __restrict__ b1,
                  const float* __restrict__ b2,
                  float* __restrict__ baseline) {
  __shared__ __align__(16) _Float16 H[64 * SH];

  const int tid  = threadIdx.x;
  const long row0 = (long)blockIdx.x * 64;
  const int lane = tid & 63;
  const int wv   = tid >> 6;
  const int lm   = lane & 15;
  const int lq   = lane >> 4;

  _Float16* X = H;

  #pragma unroll
  for (int it = 0; it < 2; ++it) {
    int flat = it * 256 + tid;
    int vr = flat >> 3;
    int f0 = (flat & 7) * 8;
    floatx8 v  = *(const floatx8*)&obs[(row0 + vr) * 64 + f0];
    floatx8 m  = *(const floatx8*)&rm[f0];
    floatx8 is = *(const floatx8*)&inv_std[f0];
    half8 h;
    #pragma unroll
    for (int j = 0; j < 8; ++j)
      h[j] = (_Float16)fminf(5.f, fmaxf(-5.f, (v[j] - m[j]) * is[j]));
    *(half8*)&X[vr * SX + f0] = h;
  }

  // ---- prefetch L1 B fragments ----
  const half8* B0h = (const half8*)(frag + FR_W0V_HI);
  const half8* B0l = (const half8*)(frag + FR_W0V_LO);
  half8 B0hr[2][4], B0lr[2][4];
  #pragma unroll
  for (int ks = 0; ks < 2; ++ks)
    #pragma unroll
    for (int nt = 0; nt < 4; ++nt) {
      int ntg = wv * 4 + nt;
      B0hr[ks][nt] = B0h[(ntg * 2 + ks) * 64 + lane];
      B0lr[ks][nt] = B0l[(ntg * 2 + ks) * 64 + lane];
    }
  __syncthreads();

  floatx4 acc[4][4];

  #pragma unroll
  for (int mt = 0; mt < 4; ++mt)
    #pragma unroll
    for (int nt = 0; nt < 4; ++nt) acc[mt][nt] = (floatx4){0.f,0.f,0.f,0.f};
  #pragma unroll
  for (int ks = 0; ks < 2; ++ks) {
    half8 A[4];
    #pragma unroll
    for (int mt = 0; mt < 4; ++mt)
      A[mt] = *(const half8*)&X[(mt * 16 + lm) * SX + ks * 32 + lq * 8];
    __builtin_amdgcn_s_setprio(1);
    #pragma unroll
    for (int mt = 0; mt < 4; ++mt)
      #pragma unroll
      for (int nt = 0; nt < 4; ++nt)
        acc[mt][nt] = __builtin_amdgcn_mfma_f32_16x16x32_f16(B0hr[ks][nt], A[mt], acc[mt][nt], 0, 0, 0);
    #pragma unroll
    for (int mt = 0; mt < 4; ++mt)
      #pragma unroll
      for (int nt = 0; nt < 4; ++nt)
        acc[mt][nt] = __builtin_amdgcn_mfma_f32_16x16x32_f16(B0lr[ks][nt], A[mt], acc[mt][nt], 0, 0, 0);
    __builtin_amdgcn_s_setprio(0);
  }

  // ---- prefetch L2 ks=0 B fragments ----
  const half8* B1h = (const half8*)(frag + FR_W1V_HI);
  const half8* B1l = (const half8*)(frag + FR_W1V_LO);
  half8 Bh[4], Bl[4], Bhn[4], Bln[4];
  #pragma unroll
  for (int nt = 0; nt < 4; ++nt) {
    int ntg = wv * 4 + nt;
    Bh[nt] = B1h[(ntg * 8) * 64 + lane];
    Bl[nt] = B1l[(ntg * 8) * 64 + lane];
  }

  __syncthreads();
  #pragma unroll
  for (int nt = 0; nt < 4; ++nt) {
    int colbase = (wv * 4 + nt) * 16 + lq * 4;
    floatx4 bias = *(const floatx4*)&b0[colbase];
    #pragma unroll
    for (int mt = 0; mt < 4; ++mt) {
      int row = mt * 16 + lm;
      half4 h;
      #pragma unroll
      for (int reg = 0; reg < 4; ++reg)
        h[reg] = (_Float16)silu_f(acc[mt][nt][reg] + bias[reg]);
      *(half4*)&H[row * SH + colbase] = h;
    }
  }
  __syncthreads();

  #pragma unroll
  for (int mt = 0; mt < 4; ++mt)
    #pragma unroll
    for (int nt = 0; nt < 4; ++nt) acc[mt][nt] = (floatx4){0.f,0.f,0.f,0.f};
  #pragma unroll
  for (int ks = 0; ks < 8; ++ks) {
    if (ks < 7) {
      #pragma unroll
      for (int nt = 0; nt < 4; ++nt) {
        int ntg = wv * 4 + nt;
        Bhn[nt] = B1h[(ntg * 8 + ks + 1) * 64 + lane];
        Bln[nt] = B1l[(ntg * 8 + ks + 1) * 64 + lane];
      }
    }
    half8 A[4];
    #pragma unroll
    for (int mt = 0; mt < 4; ++mt)
      A[mt] = *(const half8*)&H[(mt * 16 + lm) * SH + ks * 32 + lq * 8];
    __builtin_amdgcn_s_setprio(1);
    #pragma unroll
    for (int mt = 0; mt < 4; ++mt)
      #pragma unroll
      for (int nt = 0; nt < 4; ++nt)
        acc[mt][nt] = __builtin_amdgcn_mfma_f32_16x16x32_f16(Bh[nt], A[mt], acc[mt][nt], 0, 0, 0);
    #pragma unroll
    for (int mt = 0; mt < 4; ++mt)
      #pragma unroll
      for (int nt = 0; nt < 4; ++nt)
        acc[mt][nt] = __builtin_amdgcn_mfma_f32_16x16x32_f16(Bl[nt], A[mt], acc[mt][nt], 0, 0, 0);
    __builtin_amdgcn_s_setprio(0);
    if (ks < 7) {
      #pragma unroll
      for (int nt = 0; nt < 4; ++nt) { Bh[nt] = Bhn[nt]; Bl[nt] = Bln[nt]; }
    }
  }

  // ---- prefetch ALL L3 B fragments ----
  const half8* B2h = (const half8*)(frag + FR_W2V_HI);
  const half8* B2l = (const half8*)(frag + FR_W2V_LO);
  half8 B2hr[8], B2lr[8];
  #pragma unroll
  for (int ks = 0; ks < 8; ++ks) {
    B2hr[ks] = B2h[ks * 64 + lane];
    B2lr[ks] = B2l[ks * 64 + lane];
  }

  __syncthreads();
  #pragma unroll
  for (int nt = 0; nt < 4; ++nt) {
    int colbase = (wv * 4 + nt) * 16 + lq * 4;
    floatx4 bias = *(const floatx4*)&b1[colbase];
    #pragma unroll
    for (int mt = 0; mt < 4; ++mt) {
      int row = mt * 16 + lm;
      half4 h;
      #pragma unroll
      for (int reg = 0; reg < 4; ++reg)
        h[reg] = (_Float16)silu_f(acc[mt][nt][reg] + bias[reg]);
      *(half4*)&H[row * SH + colbase] = h;
    }
  }
  __syncthreads();

  {
    floatx4 c3a = (floatx4){0.f,0.f,0.f,0.f};
    floatx4 c3b = (floatx4){0.f,0.f,0.f,0.f};
    __builtin_amdgcn_s_setprio(1);
    #pragma unroll
    for (int ks = 0; ks < 8; ks += 2) {
      half8 A0 = *(const half8*)&H[(wv * 16 + lm) * SH + ks * 32 + lq * 8];
      half8 A1 = *(const half8*)&H[(wv * 16 + lm) * SH + (ks + 1) * 32 + lq * 8];
      c3a = __builtin_amdgcn_mfma_f32_16x16x32_f16(B2hr[ks],     A0, c3a, 0, 0, 0);
      c3b = __builtin_amdgcn_mfma_f32_16x16x32_f16(B2hr[ks + 1], A1, c3b, 0, 0, 0);
      c3a = __builtin_amdgcn_mfma_f32_16x16x32_f16(B2lr[ks],     A0, c3a, 0, 0, 0);
      c3b = __builtin_amdgcn_mfma_f32_16x16x32_f16(B2lr[ks + 1], A1, c3b, 0, 0, 0);
    }
    __builtin_amdgcn_s_setprio(0);
    // D[feature][row]: feature = lq*4+reg; only feature 0 valid (lq==0, reg 0).
    // lane lm of wave wv holds baseline for row wv*16+lm.
    if (lq == 0) baseline[row0 + wv * 16 + lm] = c3a[0] + c3b[0] + b2[0];
  }
}

// ---------------- GAE segmented scan (unchanged, verified) ----------------
__global__ void gae_phase1(const float* __restrict__ reward,
                           const float* __restrict__ done,
                           const float* __restrict__ trunc,
                           const float* __restrict__ baseline,
                           float* __restrict__ A, float* __restrict__ P) {
  int s = blockIdx.x, b = threadIdx.x;
  float Aa = 0.f, Pp = 1.f;
  for (int t = (s + 1) * 32 - 1; t >= s * 32; --t) {
    int idx = t * 256 + b;
    float r = reward[idx], d = done[idx], tr = trunc[idx];
    float tm = 1.f - tr;
    float te = d * tm;
    float bl = baseline[idx], bl1 = baseline[idx + 256];
    float g1 = GAMMA_ * (1.f - te);
    float delta = (r + g1 * bl1 - bl) * tm;
    float c = g1 * tm * LAM_;
    Aa = delta + c * Aa;
    Pp = c * Pp;
  }
  A[s * 256 + b] = Aa;
  P[s * 256 + b] = Pp;
}

__global__ void gae_phase2(const float* __restrict__ A,
                           const float* __restrict__ P,
                           float* __restrict__ seedv) {
  int b = threadIdx.x;
  float acc = 0.f;
  for (int s = 31; s >= 0; --s) {
    seedv[s * 256 + b] = acc;
    acc = A[s * 256 + b] + P[s * 256 + b] * acc;
  }
}

__global__ void gae_phase3(const float* __restrict__ reward,
                           const float* __restrict__ done,
                           const float* __restrict__ trunc,
                           const float* __restrict__ baseline,
                           const float* __restrict__ seedv,
                           float* __restrict__ adv,
                           float* __restrict__ accum) {
  __shared__ float red[12];
  int s = blockIdx.x, b = threadIdx.x;
  float acc = seedv[s * 256 + b];
  int tend = (s + 1) * 32;
  float vnext = baseline[tend * 256 + b];
  float vs_next = acc + vnext;
  float sa = 0.f, sa2 = 0.f, sv2 = 0.f;
  for (int t = tend - 1; t >= s * 32; --t) {
    int idx = t * 256 + b;
    float r = reward[idx], d = done[idx], tr = trunc[idx];
    float tm = 1.f - tr;
    float te = d * tm;
    float bl = baseline[idx];
    float g1 = GAMMA_ * (1.f - te);
    float delta = (r + g1 * vnext - bl) * tm;
    acc = delta + g1 * tm * LAM_ * acc;
    float at = (r + g1 * vs_next - bl) * tm;
    at = fminf(1e15f, fmaxf(-1e15f, at));
    adv[idx] = at;
    sa += at; sa2 += at * at;
    sv2 += fminf(acc * acc, 1e30f);
    vs_next = acc + bl;
    vnext = bl;
  }
  float v0 = sa, v1 = sa2, v2 = sv2;
  #pragma unroll
  for (int o = 32; o > 0; o >>= 1) {
    v0 += __shfl_down(v0, o, 64);
    v1 += __shfl_down(v1, o, 64);
    v2 += __shfl_down(v2, o, 64);
  }
  int lane = threadIdx.x & 63, w = threadIdx.x >> 6;
  if (lane == 0) { red[w] = v0; red[4 + w] = v1; red[8 + w] = v2; }
  __syncthreads();
  if (threadIdx.x == 0) {
    float s0=0.f, s1=0.f, s2=0.f;
    for (int q = 0; q < 4; ++q) { s0 += red[q]; s1 += red[4+q]; s2 += red[8+q]; }
    atomicAdd(&accum[3], s0);
    atomicAdd(&accum[4], s1);
    atomicAdd(&accum[5], s2);
  }
}

// ---------------- finalize ----------------
__global__ void finalize_kernel(const float* __restrict__ accum,
                                float* __restrict__ out) {
  float N = (float)ROWS_P;
  float kl_learner = accum[0] / N;
  float kl_guider  = accum[1] / N;
  float entropy    = accum[2] / N;
  float v_loss     = 0.25f * accum[5] / N;
  float gp_loss    = -accum[6] / N;
  float lp_loss    = -accum[7] / N;
  float learner_loss = kl_learner + lp_loss;      // ALPHA = 1
  float guider_loss  = kl_guider + gp_loss;
  float total = learner_loss + guider_loss + v_loss - 0.01f * entropy;
  out[0] = total;
  out[1] = guider_loss;
  out[2] = learner_loss;
  out[3] = kl_learner;
}

extern "C" void kernel_launch(void* const* d_in, const int* in_sizes, int n_in,
                              void* d_out, int out_size, void* d_ws, size_t ws_size,
                              hipStream_t stream) {
  (void)in_sizes; (void)n_in; (void)out_size; (void)ws_size;
  const float* obs    = (const float*)d_in[0];
  const float* pobs   = (const float*)d_in[1];
  const float* reward = (const float*)d_in[2];
  const float* done   = (const float*)d_in[3];
  const float* trunc  = (const float*)d_in[4];
  const float* logits = (const float*)d_in[5];
  const float* action = (const float*)d_in[6];
  const float* noise  = (const float*)d_in[7];
  const float* pw0 = (const float*)d_in[8];
  const float* pb0 = (const float*)d_in[9];
  const float* pw1 = (const float*)d_in[10];
  const float* pb1 = (const float*)d_in[11];
  const float* pw2 = (const float*)d_in[12];
  const float* pb2 = (const float*)d_in[13];
  const float* vw0 = (const float*)d_in[14];
  const float* vb0 = (const float*)d_in[15];
  const float* vw1 = (const float*)d_in[16];
  const float* vb1 = (const float*)d_in[17];
  const float* vw2 = (const float*)d_in[18];
  const float* vb2 = (const float*)d_in[19];
  const float* rm  = (const float*)d_in[20];
  const float* rv  = (const float*)d_in[21];

  u16*   frag  = (u16*)d_ws;
  float* fbase = (float*)d_ws + FR_TOTAL / 2;
  float* accum   = fbase + WS_ACC;
  float* inv_std = fbase + WS_INV;
  float* adv     = fbase + WS_ADV;
  float* base    = fbase + WS_BASE;
  float* gA      = fbase + WS_GA;
  float* gP      = fbase + WS_GP;
  float* gS      = fbase + WS_GS;
  float* out = (float*)d_out;

  prep_kernel<<<1, 256, 0, stream>>>(rv, inv_std, accum);
  convert_kernel<<<672, 256, 0, stream>>>(pw0, pw1, pw2, vw0, vw1, vw2, frag);

  value_kernel<<<(int)(ROWS_V / 64), 256, 0, stream>>>(
      obs, rm, inv_std, frag, vb0, vb1, vb2, base);

  gae_phase1<<<32, 256, 0, stream>>>(reward, done, trunc, base, gA, gP);
  gae_phase2<<<1, 256, 0, stream>>>(gA, gP, gS);
  gae_phase3<<<32, 256, 0, stream>>>(reward, done, trunc, base, gS, adv, accum);

  policy_kernel<<<(int)(ROWS_P / 32), 256, 0, stream>>>(
      obs, pobs, rm, inv_std, frag, pb0, pb1, pb2,
      logits, action, noise, adv, accum);

  finalize_kernel<<<1, 1, 0, stream>>>(accum, out);
}

// Round 4
// 504.161 us; speedup vs baseline: 2.7227x; 1.6121x over previous
//
#include <hip/hip_runtime.h>
#include <math.h>

#define GAMMA_   0.97f
#define LAM_     0.95f
#define EPSILON_ 0.3f
#define HLOG2PI_ 0.91893853320467274f
#define LOG2C_   0.69314718055994531f
#define LOG1P2_  0.18232155679395463f
#define LOG0P8_  (-0.22314355131420976f)

typedef unsigned short u16;
typedef unsigned int   u32;
typedef _Float16 half8 __attribute__((ext_vector_type(8)));
typedef _Float16 half4 __attribute__((ext_vector_type(4)));
typedef __attribute__((ext_vector_type(4))) float floatx4;
typedef __attribute__((ext_vector_type(8))) float floatx8;

constexpr int  TT     = 1024;
constexpr long ROWS_P = (long)TT * 256;          // 262144
constexpr long ROWS_V = (long)(TT + 1) * 256;    // 262400

// ---- fragment workspace layout (u16 offsets from ws base) ----
constexpr long FR_W0P_HI = 0;        // NT16 KS2  -> 16384
constexpr long FR_W0P_LO = 16384;
constexpr long FR_W1P_HI = 32768;    // NT16 KS8  -> 65536
constexpr long FR_W1P_LO = 98304;
constexpr long FR_W2P_HI = 163840;   // NT1  KS8  -> 4096
constexpr long FR_W2P_LO = 167936;
constexpr long FR_W0V_HI = 172032;
constexpr long FR_W0V_LO = 188416;
constexpr long FR_W1V_HI = 204800;
constexpr long FR_W1V_LO = 270336;
constexpr long FR_W2V_HI = 335872;
constexpr long FR_W2V_LO = 339968;
constexpr long FR_TOTAL  = 344064;   // u16 elems

// ---- float workspace (offsets from (float*)ws + FR_TOTAL/2) ----
constexpr long WS_ACC  = 0;                 // 32
constexpr long WS_INV  = 32;                // 64
constexpr long WS_ADV  = 96;                // 262144
constexpr long WS_BASE = WS_ADV + ROWS_P;   // 262400
constexpr long WS_GA   = WS_BASE + ROWS_V;  // 8192
constexpr long WS_GP   = WS_GA + 8192;
constexpr long WS_GS   = WS_GP + 8192;
constexpr long WS_BANK = WS_GS + 8192;      // 32 banks x 8 slots = 256

// accum slots: 0 kl_sum, 1 kl_m_sum, 2 ent_sum, 3 adv_sum, 4 adv2_sum,
//              5 vmx2_sum, 6 gp_sum, 7 lp_sum
// policy-written slots (0,1,2,6,7) go to banked accumB to avoid
// same-line atomic serialization from 8192 blocks.

__device__ __forceinline__ float softplus_f(float x) {
  return (x > 20.f) ? x : log1pf(expf(x));
}
// silu: result is truncated to fp16 downstream, so v_rcp_f32 (~2^-22 rel err)
// is exact at the storage precision and saves the precise-div sequence.
__device__ __forceinline__ float silu_f(float x) {
  return x * __builtin_amdgcn_rcpf(1.f + __expf(-x));
}
__device__ __forceinline__ float clamp30(float x) {
  return fminf(1e30f, fmaxf(-1e30f, x));
}

// ---------------- prep ----------------
__global__ void prep_kernel(const float* __restrict__ rv,
                            float* __restrict__ inv_std,
                            float* __restrict__ accum,
                            float* __restrict__ accumB) {
  int t = threadIdx.x;
  if (t < 32) accum[t] = 0.f;
  accumB[t] = 0.f;                 // 256 threads cover 32x8
  if (t < 64) {
    float var = rv[t] / 1000001.0f;
    var = fminf(1e6f, fmaxf(1e-6f, var));
    inv_std[t] = 1.f / sqrtf(var);
  }
}

// ---------------- weight -> split-fp16 MFMA fragments ----------------
__global__ void convert_kernel(const float* __restrict__ pw0,
                               const float* __restrict__ pw1,
                               const float* __restrict__ pw2,
                               const float* __restrict__ vw0,
                               const float* __restrict__ vw1,
                               const float* __restrict__ vw2,
                               u16* __restrict__ frag) {
  int idx = blockIdx.x * 256 + threadIdx.x;   // 0..172031
  const float* W; int kslog, K, nvalid; long hioff, looff; int e;
  if (idx < 16384)       { W = pw0; e = idx;          kslog = 1; K = 64;  nvalid = 256; hioff = FR_W0P_HI; looff = FR_W0P_LO; }
  else if (idx < 81920)  { W = pw1; e = idx - 16384;  kslog = 3; K = 256; nvalid = 256; hioff = FR_W1P_HI; looff = FR_W1P_LO; }
  else if (idx < 86016)  { W = pw2; e = idx - 81920;  kslog = 3; K = 256; nvalid = 16;  hioff = FR_W2P_HI; looff = FR_W2P_LO; }
  else if (idx < 102400) { W = vw0; e = idx - 86016;  kslog = 1; K = 64;  nvalid = 256; hioff = FR_W0V_HI; looff = FR_W0V_LO; }
  else if (idx < 167936) { W = vw1; e = idx - 102400; kslog = 3; K = 256; nvalid = 256; hioff = FR_W1V_HI; looff = FR_W1V_LO; }
  else                   { W = vw2; e = idx - 167936; kslog = 3; K = 256; nvalid = 1;   hioff = FR_W2V_HI; looff = FR_W2V_LO; }
  int j    = e & 7;
  int lane = (e >> 3) & 63;
  int ks   = (e >> 9) & ((1 << kslog) - 1);
  int nt   = e >> (9 + kslog);
  int n = nt * 16 + (lane & 15);
  int k = ks * 32 + ((lane >> 4) << 3) + j;
  float w = (n < nvalid) ? W[n * K + k] : 0.f;
  _Float16 hi = (_Float16)w;
  _Float16 lo = (_Float16)(w - (float)hi);
  frag[hioff + e] = *(u16*)&hi;
  frag[looff + e] = *(u16*)&lo;
}

// LDS strides (fp16 units); multiples of 8 (16B-aligned rows)
constexpr int SX = 72;    // X row stride
constexpr int SH = 264;   // H row stride

// =====================================================================
// Policy: block = 32 obs rows (vrows 0..31) + same 32 pobs rows (32..63).
// 4 waves; wave wv owns ntile quarter (4 ntiles = 64 cols) x ALL 4 mtiles.
// Swapped MFMA operands (W as A, X as B): thread's 4 acc regs = 4
// consecutive features of one row -> packed ds_write_b64 epilogues.
// R4: epilogue-input prefetch at block start (hide tail HBM latency),
// banked final atomics, L2 ks-loop de-unrolled (I-cache footprint).
// =====================================================================
__global__ __launch_bounds__(256, 3)
void policy_kernel(const float* __restrict__ obs,
                   const float* __restrict__ pobs,
                   const float* __restrict__ rm,
                   const float* __restrict__ inv_std,
                   const u16* __restrict__ frag,
                   const float* __restrict__ b0,
                   const float* __restrict__ b1,
                   const float* __restrict__ b2,
                   const float* __restrict__ logits,
                   const float* __restrict__ action,
                   const float* __restrict__ noise,
                   const float* __restrict__ adv,
                   const float* __restrict__ accum,
                   float* __restrict__ accumB) {
  __shared__ __align__(16) _Float16 H[64 * SH];   // 33792 B, X aliases in
  __shared__ __align__(16) float OUTT[64 * 16];
  __shared__ float red[160];

  const int tid  = threadIdx.x;
  const long row0 = (long)blockIdx.x * 32;
  const int lane = tid & 63;
  const int wv   = tid >> 6;         // ntile quarter
  const int lm   = lane & 15;
  const int lq   = lane >> 4;

  _Float16* X = H;                   // X dead after L1 MFMA

  // ---- stage normalized X (vrows 0..31 obs, 32..63 pobs), vectorized ----
  #pragma unroll
  for (int it = 0; it < 2; ++it) {
    int flat = it * 256 + tid;       // 512 groups of 8 floats
    int vr = flat >> 3;
    int f0 = (flat & 7) * 8;
    const float* src = (vr < 32) ? obs : pobs;
    floatx8 v  = *(const floatx8*)&src[(row0 + (vr & 31)) * 64 + f0];
    floatx8 m  = *(const floatx8*)&rm[f0];
    floatx8 is = *(const floatx8*)&inv_std[f0];
    half8 h;
    #pragma unroll
    for (int j = 0; j < 8; ++j)
      h[j] = (_Float16)fminf(5.f, fmaxf(-5.f, (v[j] - m[j]) * is[j]));
    *(half8*)&X[vr * SX + f0] = h;
  }

  // ---- early prefetch of epilogue inputs (independent of MLP; hides
  //      the block-tail HBM latency under the whole forward pass) ----
  const int  er   = tid >> 3;
  const int  ed   = tid & 7;
  const long erow = row0 + er;
  float pf_a   = action[erow * 8 + ed];
  float pf_loc = logits[erow * 16 + ed];
  float pf_sr  = logits[erow * 16 + 8 + ed];
  float pf_nd  = noise[erow * 8 + ed];
  float pf_adv = adv[erow];
  float pf_s3  = accum[3];           // written by gae_phase3 (earlier launch)
  float pf_s4  = accum[4];

  // ---- prefetch L1 B fragments (global only, safe across barrier) ----
  const half8* B0h = (const half8*)(frag + FR_W0P_HI);
  const half8* B0l = (const half8*)(frag + FR_W0P_LO);
  half8 B0hr[2][4], B0lr[2][4];
  #pragma unroll
  for (int ks = 0; ks < 2; ++ks)
    #pragma unroll
    for (int nt = 0; nt < 4; ++nt) {
      int ntg = wv * 4 + nt;
      B0hr[ks][nt] = B0h[(ntg * 2 + ks) * 64 + lane];
      B0lr[ks][nt] = B0l[(ntg * 2 + ks) * 64 + lane];
    }
  __syncthreads();

  floatx4 acc[4][4];

  // ---- layer 1: K=64 (2 ksteps); D = W*X^T (swapped operands) ----
  #pragma unroll
  for (int mt = 0; mt < 4; ++mt)
    #pragma unroll
    for (int nt = 0; nt < 4; ++nt) acc[mt][nt] = (floatx4){0.f,0.f,0.f,0.f};
  #pragma unroll
  for (int ks = 0; ks < 2; ++ks) {
    half8 A[4];
    #pragma unroll
    for (int mt = 0; mt < 4; ++mt)
      A[mt] = *(const half8*)&X[(mt * 16 + lm) * SX + ks * 32 + lq * 8];
    __builtin_amdgcn_s_setprio(1);
    #pragma unroll
    for (int mt = 0; mt < 4; ++mt)
      #pragma unroll
      for (int nt = 0; nt < 4; ++nt)
        acc[mt][nt] = __builtin_amdgcn_mfma_f32_16x16x32_f16(B0hr[ks][nt], A[mt], acc[mt][nt], 0, 0, 0);
    #pragma unroll
    for (int mt = 0; mt < 4; ++mt)
      #pragma unroll
      for (int nt = 0; nt < 4; ++nt)
        acc[mt][nt] = __builtin_amdgcn_mfma_f32_16x16x32_f16(B0lr[ks][nt], A[mt], acc[mt][nt], 0, 0, 0);
    __builtin_amdgcn_s_setprio(0);
  }

  // ---- prefetch L2 ks=0 B fragments before the epilogue barrier ----
  const half8* B1h = (const half8*)(frag + FR_W1P_HI);
  const half8* B1l = (const half8*)(frag + FR_W1P_LO);
  half8 Bh[4], Bl[4], Bhn[4], Bln[4];
  #pragma unroll
  for (int nt = 0; nt < 4; ++nt) {
    int ntg = wv * 4 + nt;
    Bh[nt] = B1h[(ntg * 8) * 64 + lane];
    Bl[nt] = B1l[(ntg * 8) * 64 + lane];
  }

  __syncthreads();              // all waves done reading X (H1 aliases it)
  // acc[mt][nt][reg]: row = mt*16+lm, feature = (wv*4+nt)*16 + lq*4 + reg
  #pragma unroll
  for (int nt = 0; nt < 4; ++nt) {
    int colbase = (wv * 4 + nt) * 16 + lq * 4;
    floatx4 bias = *(const floatx4*)&b0[colbase];
    #pragma unroll
    for (int mt = 0; mt < 4; ++mt) {
      int row = mt * 16 + lm;
      half4 h;
      #pragma unroll
      for (int reg = 0; reg < 4; ++reg)
        h[reg] = (_Float16)silu_f(acc[mt][nt][reg] + bias[reg]);
      *(half4*)&H[row * SH + colbase] = h;
    }
  }
  __syncthreads();

  // ---- layer 2: K=256 (8 ksteps), B double-buffered; NOT unrolled
  //      (I-cache footprint: this is the fattest region of the kernel) ----
  #pragma unroll
  for (int mt = 0; mt < 4; ++mt)
    #pragma unroll
    for (int nt = 0; nt < 4; ++nt) acc[mt][nt] = (floatx4){0.f,0.f,0.f,0.f};
  #pragma unroll 1
  for (int ks = 0; ks < 8; ++ks) {
    if (ks < 7) {
      #pragma unroll
      for (int nt = 0; nt < 4; ++nt) {
        int ntg = wv * 4 + nt;
        Bhn[nt] = B1h[(ntg * 8 + ks + 1) * 64 + lane];
        Bln[nt] = B1l[(ntg * 8 + ks + 1) * 64 + lane];
      }
    }
    half8 A[4];
    #pragma unroll
    for (int mt = 0; mt < 4; ++mt)
      A[mt] = *(const half8*)&H[(mt * 16 + lm) * SH + ks * 32 + lq * 8];
    __builtin_amdgcn_s_setprio(1);
    #pragma unroll
    for (int mt = 0; mt < 4; ++mt)
      #pragma unroll
      for (int nt = 0; nt < 4; ++nt)
        acc[mt][nt] = __builtin_amdgcn_mfma_f32_16x16x32_f16(Bh[nt], A[mt], acc[mt][nt], 0, 0, 0);
    #pragma unroll
    for (int mt = 0; mt < 4; ++mt)
      #pragma unroll
      for (int nt = 0; nt < 4; ++nt)
        acc[mt][nt] = __builtin_amdgcn_mfma_f32_16x16x32_f16(Bl[nt], A[mt], acc[mt][nt], 0, 0, 0);
    __builtin_amdgcn_s_setprio(0);
    if (ks < 7) {
      #pragma unroll
      for (int nt = 0; nt < 4; ++nt) { Bh[nt] = Bhn[nt]; Bl[nt] = Bln[nt]; }
    }
  }

  // ---- prefetch ALL L3 B fragments before the epilogue barrier ----
  const half8* B2h = (const half8*)(frag + FR_W2P_HI);
  const half8* B2l = (const half8*)(frag + FR_W2P_LO);
  half8 B2hr[8], B2lr[8];
  #pragma unroll
  for (int ks = 0; ks < 8; ++ks) {
    B2hr[ks] = B2h[ks * 64 + lane];
    B2lr[ks] = B2l[ks * 64 + lane];
  }

  __syncthreads();              // all waves done reading H1
  #pragma unroll
  for (int nt = 0; nt < 4; ++nt) {
    int colbase = (wv * 4 + nt) * 16 + lq * 4;
    floatx4 bias = *(const floatx4*)&b1[colbase];
    #pragma unroll
    for (int mt = 0; mt < 4; ++mt) {
      int row = mt * 16 + lm;
      half4 h;
      #pragma unroll
      for (int reg = 0; reg < 4; ++reg)
        h[reg] = (_Float16)silu_f(acc[mt][nt][reg] + bias[reg]);
      *(half4*)&H[row * SH + colbase] = h;
    }
  }
  __syncthreads();

  // ---- layer 3: N=16, K=256; wave wv handles mtile wv ----
  {
    floatx4 c3a = (floatx4){0.f,0.f,0.f,0.f};
    floatx4 c3b = (floatx4){0.f,0.f,0.f,0.f};
    __builtin_amdgcn_s_setprio(1);
    #pragma unroll
    for (int ks = 0; ks < 8; ks += 2) {
      half8 A0 = *(const half8*)&H[(wv * 16 + lm) * SH + ks * 32 + lq * 8];
      half8 A1 = *(const half8*)&H[(wv * 16 + lm) * SH + (ks + 1) * 32 + lq * 8];
      c3a = __builtin_amdgcn_mfma_f32_16x16x32_f16(B2hr[ks],     A0, c3a, 0, 0, 0);
      c3b = __builtin_amdgcn_mfma_f32_16x16x32_f16(B2hr[ks + 1], A1, c3b, 0, 0, 0);
      c3a = __builtin_amdgcn_mfma_f32_16x16x32_f16(B2lr[ks],     A0, c3a, 0, 0, 0);
      c3b = __builtin_amdgcn_mfma_f32_16x16x32_f16(B2lr[ks + 1], A1, c3b, 0, 0, 0);
    }
    __builtin_amdgcn_s_setprio(0);
    // D[feature][row]: row = wv*16+lm, features = lq*4 + reg (contig)
    floatx4 bias = *(const floatx4*)&b2[lq * 4];
    *(floatx4*)&OUTT[(wv * 16 + lm) * 16 + lq * 4] = c3a + c3b + bias;
  }
  __syncthreads();

  // ---- epilogue: parallel over (row, d): tid = r*8 + d ----
  {
    int r = er;                // tid >> 3
    int d = ed;                // tid & 7

    float gl  = OUTT[r * 16 + d];
    float gsr = OUTT[r * 16 + 8 + d];
    float ll  = OUTT[(32 + r) * 16 + d];
    float lsr = OUTT[(32 + r) * 16 + 8 + d];
    float a   = pf_a;
    float loc = pf_loc;
    float sr  = pf_sr;
    float nd  = pf_nd;

    float gs = softplus_f(gsr) + 1e-3f;
    float ls = softplus_f(lsr) + 1e-3f;
    float sc = softplus_f(sr) + 1e-3f;
    float ldj = 2.f * (LOG2C_ - a - softplus_f(-2.f * a));
    float lgs = logf(gs), lls = logf(ls), lsc = logf(sc);
    float zg = (a - gl) / gs;
    float zl = (a - ll) / ls;
    float z  = (a - loc) / sc;
    float glp = -0.5f * zg * zg - lgs - HLOG2PI_ - ldj;
    float llp = -0.5f * zl * zl - lls - HLOG2PI_ - ldj;
    float blp = -0.5f * z * z - lsc - HLOG2PI_ - ldj;
    float ratio = gs / ls;
    float vr = ratio * ratio;
    float t1 = (gl - ll) / ls; t1 *= t1;
    float kl = 0.5f * (vr + t1 - 1.f) - (lgs - lls);
    float dist = loc + sc * nd;
    float ent = 0.5f + HLOG2PI_ + lsc
              + 2.f * (LOG2C_ - dist - softplus_f(-2.f * dist));

    // reduce over d (8 adjacent lanes)
    #pragma unroll
    for (int o = 4; o > 0; o >>= 1) {
      glp += __shfl_down(glp, o, 8);
      llp += __shfl_down(llp, o, 8);
      blp += __shfl_down(blp, o, 8);
      kl  += __shfl_down(kl, o, 8);
      ent += __shfl_down(ent, o, 8);
    }

    if (d == 0) {
      kl *= 0.125f;
      kl  = clamp30(kl);
      ent = clamp30(ent);

      float diff = glp - llp;
      float m = (diff > LOG1P2_ || diff < LOG0P8_) ? 1.f : 0.f;

      float N = (float)ROWS_P;
      float sum = pf_s3, sumsq = pf_s4;
      float mean = sum / N;
      float var  = fmaxf((sumsq - sum * sum / N) / (N - 1.f), 0.f);
      float inv  = 1.f / (sqrtf(var) + 1e-5f);
      float a_n  = (pf_adv - mean) * inv;

      float rho = expf(fminf(glp - blp, 80.f));
      float cl  = fminf(LOG1P2_, fmaxf(LOG0P8_, diff));
      float rc  = expf(fminf(cl + llp - blp, 80.f));
      rc = fminf(1.f + EPSILON_, fmaxf(1.f - EPSILON_, rc));
      float gp = clamp30(fminf(rho * a_n, rc * a_n));

      float rho2 = expf(fminf(llp - blp, 10.f));
      float r2c  = fminf(1.f + EPSILON_, fmaxf(1.f - EPSILON_, rho2));
      float lp = clamp30(fminf(rho2 * a_n, r2c * a_n));

      red[r]       = kl;
      red[32 + r]  = kl * m;
      red[64 + r]  = ent;
      red[96 + r]  = gp;
      red[128 + r] = lp;
    }
  }
  __syncthreads();
  if (tid < 32) {
    float s0 = red[tid], s1 = red[32 + tid], s2 = red[64 + tid];
    float s3 = red[96 + tid], s4 = red[128 + tid];
    #pragma unroll
    for (int o = 16; o > 0; o >>= 1) {
      s0 += __shfl_down(s0, o, 32);
      s1 += __shfl_down(s1, o, 32);
      s2 += __shfl_down(s2, o, 32);
      s3 += __shfl_down(s3, o, 32);
      s4 += __shfl_down(s4, o, 32);
    }
    if (tid == 0) {
      float* bank = accumB + (blockIdx.x & 31) * 8;
      atomicAdd(&bank[0], s0);
      atomicAdd(&bank[1], s1);
      atomicAdd(&bank[2], s2);
      atomicAdd(&bank[6], s3);
      atomicAdd(&bank[7], s4);
    }
  }
}

// =====================================================================
// Value: block = 64 obs rows, same structure; swapped MFMA operands,
// packed epilogues; L3 writes baseline directly from registers.
// =====================================================================
__global__ __launch_bounds__(256, 3)
void value_kernel(const float* __restrict__ obs,
                  const float* __restrict__ rm,
                  const float* __restrict__ inv_std,
                  const u16* __restrict__ frag,
                  const float* __restrict__ b0,
                  const float* __restrict__ b1,
                  const float* __restrict__ b2,
                  float* __restrict__ baseline) {
  __shared__ __align__(16) _Float16 H[64 * SH];

  const int tid  = threadIdx.x;
  const long row0 = (long)blockIdx.x * 64;
  const int lane = tid & 63;
  const int wv   = tid >> 6;
  const int lm   = lane & 15;
  const int lq   = lane >> 4;

  _Float16* X = H;

  #pragma unroll
  for (int it = 0; it < 2; ++it) {
    int flat = it * 256 + tid;
    int vr = flat >> 3;
    int f0 = (flat & 7) * 8;
    floatx8 v  = *(const floatx8*)&obs[(row0 + vr) * 64 + f0];
    floatx8 m  = *(const floatx8*)&rm[f0];
    floatx8 is = *(const floatx8*)&inv_std[f0];
    half8 h;
    #pragma unroll
    for (int j = 0; j < 8; ++j)
      h[j] = (_Float16)fminf(5.f, fmaxf(-5.f, (v[j] - m[j]) * is[j]));
    *(half8*)&X[vr * SX + f0] = h;
  }

  // ---- prefetch L1 B fragments ----
  const half8* B0h = (const half8*)(frag + FR_W0V_HI);
  const half8* B0l = (const half8*)(frag + FR_W0V_LO);
  half8 B0hr[2][4], B0lr[2][4];
  #pragma unroll
  for (int ks = 0; ks < 2; ++ks)
    #pragma unroll
    for (int nt = 0; nt < 4; ++nt) {
      int ntg = wv * 4 + nt;
      B0hr[ks][nt] = B0h[(ntg * 2 + ks) * 64 + lane];
      B0lr[ks][nt] = B0l[(ntg * 2 + ks) * 64 + lane];
    }
  __syncthreads();

  floatx4 acc[4][4];

  #pragma unroll
  for (int mt = 0; mt < 4; ++mt)
    #pragma unroll
    for (int nt = 0; nt < 4; ++nt) acc[mt][nt] = (floatx4){0.f,0.f,0.f,0.f};
  #pragma unroll
  for (int ks = 0; ks < 2; ++ks) {
    half8 A[4];
    #pragma unroll
    for (int mt = 0; mt < 4; ++mt)
      A[mt] = *(const half8*)&X[(mt * 16 + lm) * SX + ks * 32 + lq * 8];
    __builtin_amdgcn_s_setprio(1);
    #pragma unroll
    for (int mt = 0; mt < 4; ++mt)
      #pragma unroll
      for (int nt = 0; nt < 4; ++nt)
        acc[mt][nt] = __builtin_amdgcn_mfma_f32_16x16x32_f16(B0hr[ks][nt], A[mt], acc[mt][nt], 0, 0, 0);
    #pragma unroll
    for (int mt = 0; mt < 4; ++mt)
      #pragma unroll
      for (int nt = 0; nt < 4; ++nt)
        acc[mt][nt] = __builtin_amdgcn_mfma_f32_16x16x32_f16(B0lr[ks][nt], A[mt], acc[mt][nt], 0, 0, 0);
    __builtin_amdgcn_s_setprio(0);
  }

  // ---- prefetch L2 ks=0 B fragments ----
  const half8* B1h = (const half8*)(frag + FR_W1V_HI);
  const half8* B1l = (const half8*)(frag + FR_W1V_LO);
  half8 Bh[4], Bl[4], Bhn[4], Bln[4];
  #pragma unroll
  for (int nt = 0; nt < 4; ++nt) {
    int ntg = wv * 4 + nt;
    Bh[nt] = B1h[(ntg * 8) * 64 + lane];
    Bl[nt] = B1l[(ntg * 8) * 64 + lane];
  }

  __syncthreads();
  #pragma unroll
  for (int nt = 0; nt < 4; ++nt) {
    int colbase = (wv * 4 + nt) * 16 + lq * 4;
    floatx4 bias = *(const floatx4*)&b0[colbase];
    #pragma unroll
    for (int mt = 0; mt < 4; ++mt) {
      int row = mt * 16 + lm;
      half4 h;
      #pragma unroll
      for (int reg = 0; reg < 4; ++reg)
        h[reg] = (_Float16)silu_f(acc[mt][nt][reg] + bias[reg]);
      *(half4*)&H[row * SH + colbase] = h;
    }
  }
  __syncthreads();

  #pragma unroll
  for (int mt = 0; mt < 4; ++mt)
    #pragma unroll
    for (int nt = 0; nt < 4; ++nt) acc[mt][nt] = (floatx4){0.f,0.f,0.f,0.f};
  #pragma unroll 1
  for (int ks = 0; ks < 8; ++ks) {
    if (ks < 7) {
      #pragma unroll
      for (int nt = 0; nt < 4; ++nt) {
        int ntg = wv * 4 + nt;
        Bhn[nt] = B1h[(ntg * 8 + ks + 1) * 64 + lane];
        Bln[nt] = B1l[(ntg * 8 + ks + 1) * 64 + lane];
      }
    }
    half8 A[4];
    #pragma unroll
    for (int mt = 0; mt < 4; ++mt)
      A[mt] = *(const half8*)&H[(mt * 16 + lm) * SH + ks * 32 + lq * 8];
    __builtin_amdgcn_s_setprio(1);
    #pragma unroll
    for (int mt = 0; mt < 4; ++mt)
      #pragma unroll
      for (int nt = 0; nt < 4; ++nt)
        acc[mt][nt] = __builtin_amdgcn_mfma_f32_16x16x32_f16(Bh[nt], A[mt], acc[mt][nt], 0, 0, 0);
    #pragma unroll
    for (int mt = 0; mt < 4; ++mt)
      #pragma unroll
      for (int nt = 0; nt < 4; ++nt)
        acc[mt][nt] = __builtin_amdgcn_mfma_f32_16x16x32_f16(Bl[nt], A[mt], acc[mt][nt], 0, 0, 0);
    __builtin_amdgcn_s_setprio(0);
    if (ks < 7) {
      #pragma unroll
      for (int nt = 0; nt < 4; ++nt) { Bh[nt] = Bhn[nt]; Bl[nt] = Bln[nt]; }
    }
  }

  // ---- prefetch ALL L3 B fragments ----
  const half8* B2h = (const half8*)(frag + FR_W2V_HI);
  const half8* B2l = (const half8*)(frag + FR_W2V_LO);
  half8 B2hr[8], B2lr[8];
  #pragma unroll
  for (int ks = 0; ks < 8; ++ks) {
    B2hr[ks] = B2h[ks * 64 + lane];
    B2lr[ks] = B2l[ks * 64 + lane];
  }

  __syncthreads();
  #pragma unroll
  for (int nt = 0; nt < 4; ++nt) {
    int colbase = (wv * 4 + nt) * 16 + lq * 4;
    floatx4 bias = *(const floatx4*)&b1[colbase];
    #pragma unroll
    for (int mt = 0; mt < 4; ++mt) {
      int row = mt * 16 + lm;
      half4 h;
      #pragma unroll
      for (int reg = 0; reg < 4; ++reg)
        h[reg] = (_Float16)silu_f(acc[mt][nt][reg] + bias[reg]);
      *(half4*)&H[row * SH + colbase] = h;
    }
  }
  __syncthreads();

  {
    floatx4 c3a = (floatx4){0.f,0.f,0.f,0.f};
    floatx4 c3b = (floatx4){0.f,0.f,0.f,0.f};
    __builtin_amdgcn_s_setprio(1);
    #pragma unroll
    for (int ks = 0; ks < 8; ks += 2) {
      half8 A0 = *(const half8*)&H[(wv * 16 + lm) * SH + ks * 32 + lq * 8];
      half8 A1 = *(const half8*)&H[(wv * 16 + lm) * SH + (ks + 1) * 32 + lq * 8];
      c3a = __builtin_amdgcn_mfma_f32_16x16x32_f16(B2hr[ks],     A0, c3a, 0, 0, 0);
      c3b = __builtin_amdgcn_mfma_f32_16x16x32_f16(B2hr[ks + 1], A1, c3b, 0, 0, 0);
      c3a = __builtin_amdgcn_mfma_f32_16x16x32_f16(B2lr[ks],     A0, c3a, 0, 0, 0);
      c3b = __builtin_amdgcn_mfma_f32_16x16x32_f16(B2lr[ks + 1], A1, c3b, 0, 0, 0);
    }
    __builtin_amdgcn_s_setprio(0);
    // D[feature][row]: only feature 0 valid (lq==0, reg 0).
    if (lq == 0) baseline[row0 + wv * 16 + lm] = c3a[0] + c3b[0] + b2[0];
  }
}

// ---------------- GAE segmented scan (unchanged, verified) ----------------
__global__ void gae_phase1(const float* __restrict__ reward,
                           const float* __restrict__ done,
                           const float* __restrict__ trunc,
                           const float* __restrict__ baseline,
                           float* __restrict__ A, float* __restrict__ P) {
  int s = blockIdx.x, b = threadIdx.x;
  float Aa = 0.f, Pp = 1.f;
  for (int t = (s + 1) * 32 - 1; t >= s * 32; --t) {
    int idx = t * 256 + b;
    float r = reward[idx], d = done[idx], tr = trunc[idx];
    float tm = 1.f - tr;
    float te = d * tm;
    float bl = baseline[idx], bl1 = baseline[idx + 256];
    float g1 = GAMMA_ * (1.f - te);
    float delta = (r + g1 * bl1 - bl) * tm;
    float c = g1 * tm * LAM_;
    Aa = delta + c * Aa;
    Pp = c * Pp;
  }
  A[s * 256 + b] = Aa;
  P[s * 256 + b] = Pp;
}

__global__ void gae_phase2(const float* __restrict__ A,
                           const float* __restrict__ P,
                           float* __restrict__ seedv) {
  int b = threadIdx.x;
  float acc = 0.f;
  for (int s = 31; s >= 0; --s) {
    seedv[s * 256 + b] = acc;
    acc = A[s * 256 + b] + P[s * 256 + b] * acc;
  }
}

__global__ void gae_phase3(const float* __restrict__ reward,
                           const float* __restrict__ done,
                           const float* __restrict__ trunc,
                           const float* __restrict__ baseline,
                           const float* __restrict__ seedv,
                           float* __restrict__ adv,
                           float* __restrict__ accum) {
  __shared__ float red[12];
  int s = blockIdx.x, b = threadIdx.x;
  float acc = seedv[s * 256 + b];
  int tend = (s + 1) * 32;
  float vnext = baseline[tend * 256 + b];
  float vs_next = acc + vnext;
  float sa = 0.f, sa2 = 0.f, sv2 = 0.f;
  for (int t = tend - 1; t >= s * 32; --t) {
    int idx = t * 256 + b;
    float r = reward[idx], d = done[idx], tr = trunc[idx];
    float tm = 1.f - tr;
    float te = d * tm;
    float bl = baseline[idx];
    float g1 = GAMMA_ * (1.f - te);
    float delta = (r + g1 * vnext - bl) * tm;
    acc = delta + g1 * tm * LAM_ * acc;
    float at = (r + g1 * vs_next - bl) * tm;
    at = fminf(1e15f, fmaxf(-1e15f, at));
    adv[idx] = at;
    sa += at; sa2 += at * at;
    sv2 += fminf(acc * acc, 1e30f);
    vs_next = acc + bl;
    vnext = bl;
  }
  float v0 = sa, v1 = sa2, v2 = sv2;
  #pragma unroll
  for (int o = 32; o > 0; o >>= 1) {
    v0 += __shfl_down(v0, o, 64);
    v1 += __shfl_down(v1, o, 64);
    v2 += __shfl_down(v2, o, 64);
  }
  int lane = threadIdx.x & 63, w = threadIdx.x >> 6;
  if (lane == 0) { red[w] = v0; red[4 + w] = v1; red[8 + w] = v2; }
  __syncthreads();
  if (threadIdx.x == 0) {
    float s0=0.f, s1=0.f, s2=0.f;
    for (int q = 0; q < 4; ++q) { s0 += red[q]; s1 += red[4+q]; s2 += red[8+q]; }
    atomicAdd(&accum[3], s0);
    atomicAdd(&accum[4], s1);
    atomicAdd(&accum[5], s2);
  }
}

// ---------------- finalize (sums the 32 atomic banks) ----------------
__global__ void finalize_kernel(const float* __restrict__ accum,
                                const float* __restrict__ accumB,
                                float* __restrict__ out) {
  int t = threadIdx.x;           // 64 threads, banks on t<32
  float s0 = 0.f, s1 = 0.f, s2 = 0.f, s6 = 0.f, s7 = 0.f;
  if (t < 32) {
    const float* bank = accumB + t * 8;
    s0 = bank[0]; s1 = bank[1]; s2 = bank[2]; s6 = bank[6]; s7 = bank[7];
  }
  #pragma unroll
  for (int o = 16; o > 0; o >>= 1) {
    s0 += __shfl_down(s0, o, 64);
    s1 += __shfl_down(s1, o, 64);
    s2 += __shfl_down(s2, o, 64);
    s6 += __shfl_down(s6, o, 64);
    s7 += __shfl_down(s7, o, 64);
  }
  if (t == 0) {
    float N = (float)ROWS_P;
    float kl_learner = s0 / N;
    float kl_guider  = s1 / N;
    float entropy    = s2 / N;
    float v_loss     = 0.25f * accum[5] / N;
    float gp_loss    = -s6 / N;
    float lp_loss    = -s7 / N;
    float learner_loss = kl_learner + lp_loss;      // ALPHA = 1
    float guider_loss  = kl_guider + gp_loss;
    float total = learner_loss + guider_loss + v_loss - 0.01f * entropy;
    out[0] = total;
    out[1] = guider_loss;
    out[2] = learner_loss;
    out[3] = kl_learner;
  }
}

extern "C" void kernel_launch(void* const* d_in, const int* in_sizes, int n_in,
                              void* d_out, int out_size, void* d_ws, size_t ws_size,
                              hipStream_t stream) {
  (void)in_sizes; (void)n_in; (void)out_size; (void)ws_size;
  const float* obs    = (const float*)d_in[0];
  const float* pobs   = (const float*)d_in[1];
  const float* reward = (const float*)d_in[2];
  const float* done   = (const float*)d_in[3];
  const float* trunc  = (const float*)d_in[4];
  const float* logits = (const float*)d_in[5];
  const float* action = (const float*)d_in[6];
  const float* noise  = (const float*)d_in[7];
  const float* pw0 = (const float*)d_in[8];
  const float* pb0 = (const float*)d_in[9];
  const float* pw1 = (const float*)d_in[10];
  const float* pb1 = (const float*)d_in[11];
  const float* pw2 = (const float*)d_in[12];
  const float* pb2 = (const float*)d_in[13];
  const float* vw0 = (const float*)d_in[14];
  const float* vb0 = (const float*)d_in[15];
  const float* vw1 = (const float*)d_in[16];
  const float* vb1 = (const float*)d_in[17];
  const float* vw2 = (const float*)d_in[18];
  const float* vb2 = (const float*)d_in[19];
  const float* rm  = (const float*)d_in[20];
  const float* rv  = (const float*)d_in[21];

  u16*   frag  = (u16*)d_ws;
  float* fbase = (float*)d_ws + FR_TOTAL / 2;
  float* accum   = fbase + WS_ACC;
  float* inv_std = fbase + WS_INV;
  float* adv     = fbase + WS_ADV;
  float* base    = fbase + WS_BASE;
  float* gA      = fbase + WS_GA;
  float* gP      = fbase + WS_GP;
  float* gS      = fbase + WS_GS;
  float* accumB  = fbase + WS_BANK;
  float* out = (float*)d_out;

  prep_kernel<<<1, 256, 0, stream>>>(rv, inv_std, accum, accumB);
  convert_kernel<<<672, 256, 0, stream>>>(pw0, pw1, pw2, vw0, vw1, vw2, frag);

  value_kernel<<<(int)(ROWS_V / 64), 256, 0, stream>>>(
      obs, rm, inv_std, frag, vb0, vb1, vb2, base);

  gae_phase1<<<32, 256, 0, stream>>>(reward, done, trunc, base, gA, gP);
  gae_phase2<<<1, 256, 0, stream>>>(gA, gP, gS);
  gae_phase3<<<32, 256, 0, stream>>>(reward, done, trunc, base, gS, adv, accum);

  policy_kernel<<<(int)(ROWS_P / 32), 256, 0, stream>>>(
      obs, pobs, rm, inv_std, frag, pb0, pb1, pb2,
      logits, action, noise, adv, accum, accumB);

  finalize_kernel<<<1, 64, 0, stream>>>(accum, accumB, out);
}